// Round 7
// baseline (736.465 us; speedup 1.0000x reference)
//
#include <hip/hip_runtime.h>
#include <hip/hip_bf16.h>

typedef unsigned short u16;
typedef __attribute__((ext_vector_type(8)))  short s8v;
typedef __attribute__((ext_vector_type(4)))  short s4v;
typedef __attribute__((ext_vector_type(16))) float f16v;

#define HWX 65536
#define EPSV 1e-5f

// d_out element offsets (fp32), concatenated tuple order
#define O0 0u
#define O1 33554432u
#define O2 34340864u
#define O3 34603008u
#define O4 42467328u
#define O5 50855936u
#define O6 51118080u
#define O7 51904512u

__device__ __forceinline__ float u2f(u16 u) {
    union { unsigned int i; float f; } v; v.i = ((unsigned int)u) << 16; return v.f;
}
__device__ __forceinline__ u16 f2u(float f) {
    __hip_bfloat16 h = __float2bfloat16(f);
    return *reinterpret_cast<u16*>(&h);
}
__device__ __forceinline__ s8v ld8(const u16* p) {
    union { s8v v; s4v h[2]; } r;
    r.h[0] = *(const s4v*)p;
    r.h[1] = *(const s4v*)(p + 4);
    return r.v;
}

#define PHYS(i) ((i) + ((i) >> 5))

// ---------------- conv1: 3->64 fp32 direct (swizzled LDS), bf16 out + stats --
__global__ __launch_bounds__(256) void k_conv1(const float* __restrict__ x,
                                               const float* __restrict__ w,
                                               const float* __restrict__ bias,
                                               u16* __restrict__ out,
                                               float* __restrict__ ssum,
                                               float* __restrict__ sqsum) {
    const int h = blockIdx.x, cb = blockIdx.y, b = blockIdx.z;
    const int t = threadIdx.x;
    const int pg = t & 31, cg = t >> 5;
    const int px0 = pg * 8, c0 = cg * 4;
    const int cbase = cb * 32;

    __shared__ float xs[3][3][266];
    __shared__ float wl[27 * 33];

    float acc[4][8];
    #pragma unroll
    for (int c = 0; c < 4; c++) {
        float bv = bias[cbase + c0 + c];
        #pragma unroll
        for (int p = 0; p < 8; p++) acc[c][p] = bv;
    }

    for (int idx = t; idx < 3 * 768; idx += 256) {
        int ci = idx / 768, rem = idx - ci * 768;
        int r = rem >> 8, px = rem & 255;
        int hh = h + r - 1;
        float v = 0.f;
        if ((unsigned)hh < 256u)
            v = x[((size_t)(b * 3 + ci) * 256 + hh) * 256 + px];
        xs[ci][r][PHYS(1 + px)] = v;
    }
    if (t < 18) {
        int ci = t / 6, rr = t - ci * 6;
        xs[ci][rr >> 1][(rr & 1) ? PHYS(257) : 0] = 0.f;
    }
    for (int idx = t; idx < 27 * 32; idx += 256) {
        int co = idx / 27, rem = idx - co * 27;
        wl[rem * 33 + co] = w[(cbase + co) * 27 + rem];
    }
    __syncthreads();

    for (int ci = 0; ci < 3; ci++) {
        #pragma unroll
        for (int kh = 0; kh < 3; kh++) {
            float xv[10];
            #pragma unroll
            for (int j = 0; j < 10; j++) xv[j] = xs[ci][kh][PHYS(px0 + j)];
            float wv[3][4];
            #pragma unroll
            for (int kw = 0; kw < 3; kw++)
                #pragma unroll
                for (int c = 0; c < 4; c++)
                    wv[kw][c] = wl[(ci * 9 + kh * 3 + kw) * 33 + c0 + c];
            #pragma unroll
            for (int c = 0; c < 4; c++)
                #pragma unroll
                for (int p = 0; p < 8; p++)
                    acc[c][p] += xv[p] * wv[0][c] + xv[p + 1] * wv[1][c]
                               + xv[p + 2] * wv[2][c];
        }
    }

    #pragma unroll
    for (int c = 0; c < 4; c++) {
        int cm = cbase + c0 + c;
        u16* op = out + (((size_t)(b * 64 + cm) * 256 + h) * 256 + px0);
        #pragma unroll
        for (int p = 0; p < 8; p++) op[p] = f2u(acc[c][p]);
    }

    __syncthreads();
    float* red = &xs[0][0][0];
    #pragma unroll
    for (int c = 0; c < 4; c++) {
        float sv = 0.f, qv = 0.f;
        #pragma unroll
        for (int p = 0; p < 8; p++) { sv += acc[c][p]; qv += acc[c][p] * acc[c][p]; }
        red[(c0 + c) * 33 + pg] = sv;
        red[1056 + (c0 + c) * 33 + pg] = qv;
    }
    __syncthreads();
    if (t < 64) {
        int co = t & 31, v = t >> 5;
        const float* base = red + v * 1056 + co * 33;
        float sum = 0.f;
        #pragma unroll
        for (int i = 0; i < 32; i++) sum += base[i];
        atomicAdd((v ? sqsum : ssum) + cbase + co, sum);
    }
}

// ---------------- finalize BN1 ----------------
__global__ void k_finalize(const float* __restrict__ s, const float* __restrict__ q,
                           const float* __restrict__ g, const float* __restrict__ be,
                           float* __restrict__ sc, float* __restrict__ sh, int C) {
    int c = threadIdx.x;
    if (c >= C) return;
    const float invN = 1.f / 262144.f;
    float m = s[c] * invN;
    float v = fmaxf(q[c] * invN - m * m, 0.f);
    float scale = g[c] * rsqrtf(v + EPSV);
    sc[c] = scale;
    sh[c] = be[c] - m * scale;
}

// ---------------- BN+ReLU on bf16 buffer (in place) ----------------
__global__ __launch_bounds__(256) void k_bnrelu_h(ushort4* __restrict__ buf,
                                                  const float* __restrict__ sc,
                                                  const float* __restrict__ sh) {
    size_t i = (size_t)blockIdx.x * 256 + threadIdx.x;
    int c = (int)(i >> 14) & 63;
    float s = sc[c], h0 = sh[c];
    ushort4 r = buf[i];
    ushort4 o;
    o.x = f2u(fmaxf(u2f(r.x) * s + h0, 0.f));
    o.y = f2u(fmaxf(u2f(r.y) * s + h0, 0.f));
    o.z = f2u(fmaxf(u2f(r.z) * s + h0, 0.f));
    o.w = f2u(fmaxf(u2f(r.w) * s + h0, 0.f));
    buf[i] = o;
}

// ---------------- BN+ReLU fp32 (features, in place; finalize fused) ---------
__global__ __launch_bounds__(256) void k_bnrelu(float4* __restrict__ buf,
                                                const float* __restrict__ s,
                                                const float* __restrict__ q,
                                                const float* __restrict__ g,
                                                const float* __restrict__ be, int C) {
    size_t i = (size_t)blockIdx.x * 256 + threadIdx.x;
    int c = (int)(i >> 14) % C;
    const float invN = 1.f / 262144.f;
    float m = s[c] * invN;
    float var = fmaxf(q[c] * invN - m * m, 0.f);
    float sc = g[c] * rsqrtf(var + EPSV);
    float sh = be[c] - m * sc;
    float4 r = buf[i];
    float4 o;
    o.x = fmaxf(r.x * sc + sh, 0.f);
    o.y = fmaxf(r.y * sc + sh, 0.f);
    o.z = fmaxf(r.z * sc + sh, 0.f);
    o.w = fmaxf(r.w * sc + sh, 0.f);
    buf[i] = o;
}

// ---------------- weight pre-tiling ----------------
// match: wtile[(ch*2+plane)*9984 + (kw*64+co)*52 + kh*16+cil], ch=ci/16, 8 chunks
__global__ void k_prep_w(const float* __restrict__ wcat, u16* __restrict__ wtile) {
    int i = blockIdx.x * 256 + threadIdx.x;
    if (i >= 159744) return;
    int ch = i / 19968, rem = i - ch * 19968;
    int pl = rem / 9984; rem -= pl * 9984;
    int kwco = rem / 52, k = rem - kwco * 52;
    int kw = kwco >> 6, co = kwco & 63;
    u16 v = 0;
    if (k < 48 && co < 62) {
        int kh = k >> 4, ci = ch * 16 + (k & 15);
        float f = wcat[(size_t)co * 1152 + ci * 9 + kh * 3 + kw];
        u16 hv = f2u(f);
        v = pl ? f2u(f - u2f(hv)) : hv;
    }
    wtile[i] = v;
}
// conv2: wtile2[ch*19968 + (kw*128+co)*52 + kh*16+cil], 4 chunks of 16 ci
__global__ void k_prep_w2(const float* __restrict__ w2, u16* __restrict__ wtile2) {
    int i = blockIdx.x * 256 + threadIdx.x;
    if (i >= 79872) return;                 // 4 * 3*128*52
    int ch = i / 19968, rem = i - ch * 19968;
    int kwco = rem / 52, k = rem - kwco * 52;
    int kw = kwco >> 7, co = kwco & 127;
    u16 v = 0;
    if (k < 48) {
        int kh = k >> 4, ci = ch * 16 + (k & 15);
        v = f2u(w2[((size_t)co * 64 + ci) * 9 + kh * 3 + kw]);
    }
    wtile2[i] = v;
}
// heads: whl[ch*3840 + pl*1920 + co*20 + kloc], 12 chunks of 16 k, 96 rows (68 used)
__global__ void k_prep_wh(const float* __restrict__ qa1w, const float* __restrict__ clsw,
                          u16* __restrict__ whl) {
    int i = blockIdx.x * 256 + threadIdx.x;
    if (i >= 46080) return;
    int ch = i / 3840, rem = i - ch * 3840;
    int pl = rem / 1920; rem -= pl * 1920;
    int co = rem / 20, kloc = rem - co * 20;
    u16 v = 0;
    int k = ch * 16 + kloc;
    if (kloc < 16 && k < 190 && co < 68) {
        float f = (co < 64) ? qa1w[co * 190 + k] : clsw[(co - 64) * 190 + k];
        u16 hv = f2u(f);
        v = pl ? f2u(f - u2f(hv)) : hv;
    }
    whl[i] = v;
}

// ---- x prefetch helpers ----------------------------------------------------
__device__ __forceinline__ void load_x_c2(const u16* __restrict__ hb, int b, int ch,
                                          int h, int t, unsigned xp[24]) {
    #pragma unroll
    for (int r = 0; r < 3; r++) {
        int hh = h + r - 1;
        bool vr = (unsigned)hh < 256u;
        if (vr) {
            const u16* base = hb + ((size_t)(b * 64 + ch * 16) << 16)
                            + ((size_t)hh << 8) + t;
            #pragma unroll
            for (int ci = 0; ci < 16; ci += 2) {
                unsigned a = base[(size_t)ci << 16];
                unsigned c = base[(size_t)(ci + 1) << 16];
                xp[(r * 16 + ci) >> 1] = a | (c << 16);
            }
        } else {
            #pragma unroll
            for (int ci = 0; ci < 16; ci += 2) xp[(r * 16 + ci) >> 1] = 0u;
        }
    }
}

// h-tiled match: load 4 input rows (h0-1..h0+2) and split to packed bf16
// hi/lo planes at load time -> 32+32 u32 live regs instead of 64 f32.
__device__ __forceinline__ void load_split_match(const float* __restrict__ feat,
                                                 int b, int ch, int h0, int t,
                                                 unsigned xhi[32], unsigned xlo[32]) {
    #pragma unroll
    for (int r = 0; r < 4; r++) {
        int hh = h0 + r - 1;
        if ((unsigned)hh < 256u) {          // block-uniform branch
            const float* base = feat + ((size_t)(b * 128 + ch * 16) << 16)
                              + ((size_t)hh << 8) + t;
            float v[16];
            #pragma unroll
            for (int ci = 0; ci < 16; ci++)
                v[ci] = base[(size_t)ci << 16];
            #pragma unroll
            for (int ci = 0; ci < 16; ci += 2) {
                u16 ha = f2u(v[ci]), hb2 = f2u(v[ci + 1]);
                unsigned la = f2u(v[ci] - u2f(ha));
                unsigned lb = f2u(v[ci + 1] - u2f(hb2));
                xhi[(r * 16 + ci) >> 1] = (unsigned)ha | ((unsigned)hb2 << 16);
                xlo[(r * 16 + ci) >> 1] = la | (lb << 16);
            }
        }
    }
}

// ---------------- conv2 MFMA: 64->128, bf16 in, fp32 raw out + fused stats --
__global__ __launch_bounds__(256, 2) void k_conv2_mf(
    const u16* __restrict__ hb, const u16* __restrict__ wtile2,
    const float* __restrict__ bias, float* __restrict__ out,
    float* __restrict__ ssum, float* __restrict__ sqsum)
{
    const int h = blockIdx.x, b = blockIdx.y;
    const int t = threadIdx.x, l = t & 63, wv = t >> 6;
    const int kg = (l >> 5) * 8, nn = l & 31;

    __shared__ __align__(16) u16 xs[258 * 52];
    __shared__ __align__(16) u16 wl[3 * 128 * 52];

    f16v acc[2][4];
    #pragma unroll
    for (int pt = 0; pt < 2; pt++)
        #pragma unroll
        for (int s = 0; s < 4; s++)
            #pragma unroll
            for (int r = 0; r < 16; r++) acc[pt][s][r] = 0.f;

    // one-time zero fill (pads + out-of-range rows persist as 0)
    for (int i = t; i < 258 * 52 / 4; i += 256)
        ((ushort4*)xs)[i] = ushort4{0, 0, 0, 0};
    __syncthreads();

    unsigned xp[24];
    load_x_c2(hb, b, 0, h, t, xp);

    for (int ch = 0; ch < 4; ch++) {
        {
            const int4* src = (const int4*)(wtile2 + (size_t)ch * 19968);
            for (int i = t; i < 2496; i += 256) ((int4*)wl)[i] = src[i];
        }
        #pragma unroll
        for (int r = 0; r < 3; r++) {
            if ((unsigned)(h + r - 1) < 256u) {
                #pragma unroll
                for (int g = 0; g < 4; g++) {
                    int i0 = r * 16 + g * 4;
                    uint2 hp;
                    hp.x = xp[i0 >> 1];
                    hp.y = xp[(i0 >> 1) + 1];
                    *(uint2*)&xs[(size_t)(t + 1) * 52 + i0] = hp;
                }
            }
        }
        __syncthreads();
        if (ch < 3) load_x_c2(hb, b, ch + 1, h, t, xp);   // overlap with MFMA
        #pragma unroll
        for (int kw = 0; kw < 3; kw++) {
            #pragma unroll
            for (int ks = 0; ks < 3; ks++) {
                int k0 = ks * 16 + kg;
                s8v af[4], bf[2];
                #pragma unroll
                for (int s = 0; s < 4; s++)
                    af[s] = ld8(&wl[(kw * 128 + s * 32 + nn) * 52 + k0]);
                #pragma unroll
                for (int pt = 0; pt < 2; pt++)
                    bf[pt] = ld8(&xs[((wv * 2 + pt) * 32 + nn + kw) * 52 + k0]);
                #pragma unroll
                for (int pt = 0; pt < 2; pt++)
                    #pragma unroll
                    for (int s = 0; s < 4; s++)
                        acc[pt][s] = __builtin_amdgcn_mfma_f32_32x32x16_bf16(
                            af[s], bf[pt], acc[pt][s], 0, 0, 0);
            }
        }
        __syncthreads();
    }

    // ---- epilogue: store + fused per-channel stats (sequential ps/pq, no
    // register spike; shfl_xor off<=16 stays within each 32-lane half, so
    // hi=0 reduces px 0..31 block and hi=1 the other; both halves see the
    // same co for fixed (s,r) shifted by 4*hi) ----
    float* red = (float*)xs;       // 2 * 512 floats = 4 KB; xs dead after loop
    const int hi = l >> 5;
    const int px0 = (wv * 2 + 0) * 32 + nn;
    const int px1 = (wv * 2 + 1) * 32 + nn;
    #pragma unroll
    for (int s = 0; s < 4; s++) {
        #pragma unroll
        for (int r = 0; r < 16; r++) {
            int co = s * 32 + (r & 3) + 8 * (r >> 2) + 4 * hi;
            float bv = bias[co];
            float v0 = acc[0][s][r] + bv;
            float v1 = acc[1][s][r] + bv;
            size_t base = (((size_t)b * 128 + co) * 256 + h) * 256;
            out[base + px0] = v0;
            out[base + px1] = v1;
            float ps = v0 + v1, pq = v0 * v0 + v1 * v1;
            #pragma unroll
            for (int off = 16; off; off >>= 1) {
                ps += __shfl_xor(ps, off, 64);
                pq += __shfl_xor(pq, off, 64);
            }
            if (nn == 0) {
                int slot = (wv * 2 + hi) * 64 + s * 16 + r;
                red[slot] = ps;
                red[512 + slot] = pq;
            }
        }
    }
    __syncthreads();
    if (t < 128) {
        int co = t;
        int w32 = co & 31, si = co >> 5;
        int hib = (w32 >> 2) & 1;
        int ri = (w32 & 3) | (((w32 >> 3) & 3) << 2);
        float as = 0.f, aq = 0.f;
        #pragma unroll
        for (int w = 0; w < 4; w++) {
            int slot = (w * 2 + hib) * 64 + si * 16 + ri;
            as += red[slot];
            aq += red[512 + slot];
        }
        atomicAdd(&ssum[co], as);
        atomicAdd(&sqsum[co], aq);
    }
}

// ---------------- match MFMA: 128->62, 3-term split, h-tiled x2 -------------
__global__ __launch_bounds__(256, 2) void k_match_mf(
    const float* __restrict__ feat, const u16* __restrict__ wtile,
    float* __restrict__ out_all, float* __restrict__ out_anom)
{
    const int h0 = blockIdx.x * 2, b = blockIdx.y;
    const int t = threadIdx.x, l = t & 63, wv = t >> 6;
    const int kg = (l >> 5) * 8, nn = l & 31;

    __shared__ __align__(16) u16 xr[4 * 258 * 20];   // 41,280 B (hi then lo, per chunk)
    __shared__ __align__(16) u16 wl[2 * 9984];       // 39,936 B (hi, lo weights for chunk)

    f16v acc[2][2][2];   // [o][pt][s]
    #pragma unroll
    for (int o = 0; o < 2; o++)
        #pragma unroll
        for (int pt = 0; pt < 2; pt++)
            #pragma unroll
            for (int s = 0; s < 2; s++)
                #pragma unroll
                for (int r = 0; r < 16; r++) acc[o][pt][s][r] = 0.f;

    // one-time zero fill (px halos + out-of-range input rows persist as 0)
    for (int i = t; i < 4 * 258 * 20 / 4; i += 256)
        ((ushort4*)xr)[i] = ushort4{0, 0, 0, 0};
    __syncthreads();

    unsigned xhi[32], xlo[32];
    load_split_match(feat, b, 0, h0, t, xhi, xlo);

    for (int ch = 0; ch < 8; ch++) {
        // weights: both planes contiguous, 2496 int4
        {
            const int4* src = (const int4*)(wtile + (size_t)ch * 2 * 9984);
            for (int i = t; i < 2496; i += 256) ((int4*)wl)[i] = src[i];
        }
        // ---- hi planes write (packed b64, px slot t+1)
        #pragma unroll
        for (int r = 0; r < 4; r++) {
            if ((unsigned)(h0 + r - 1) < 256u) {       // block-uniform branch
                u16* dst = xr + r * 5160 + (t + 1) * 20;
                #pragma unroll
                for (int g = 0; g < 4; g++) {
                    uint2 hp;
                    hp.x = xhi[r * 8 + g * 2];
                    hp.y = xhi[r * 8 + g * 2 + 1];
                    *(uint2*)&dst[g * 4] = hp;
                }
            }
        }
        __syncthreads();
        // ---- hi-MFMA: Wh*Xh + Wl*Xh for both output rows
        #pragma unroll
        for (int kw = 0; kw < 3; kw++) {
            #pragma unroll
            for (int ks = 0; ks < 3; ks++) {
                int k0 = ks * 16 + kg;
                s8v ah0 = ld8(&wl[(kw * 64 + nn) * 52 + k0]);
                s8v ah1 = ld8(&wl[(kw * 64 + 32 + nn) * 52 + k0]);
                s8v al0 = ld8(&wl[9984 + (kw * 64 + nn) * 52 + k0]);
                s8v al1 = ld8(&wl[9984 + (kw * 64 + 32 + nn) * 52 + k0]);
                #pragma unroll
                for (int o = 0; o < 2; o++) {
                    #pragma unroll
                    for (int pt = 0; pt < 2; pt++) {
                        s8v xf = ld8(&xr[(ks + o) * 5160
                                         + ((wv * 2 + pt) * 32 + nn + kw) * 20 + kg]);
                        acc[o][pt][0] = __builtin_amdgcn_mfma_f32_32x32x16_bf16(ah0, xf, acc[o][pt][0], 0, 0, 0);
                        acc[o][pt][0] = __builtin_amdgcn_mfma_f32_32x32x16_bf16(al0, xf, acc[o][pt][0], 0, 0, 0);
                        acc[o][pt][1] = __builtin_amdgcn_mfma_f32_32x32x16_bf16(ah1, xf, acc[o][pt][1], 0, 0, 0);
                        acc[o][pt][1] = __builtin_amdgcn_mfma_f32_32x32x16_bf16(al1, xf, acc[o][pt][1], 0, 0, 0);
                    }
                }
            }
        }
        __syncthreads();
        // ---- lo planes write (pure unpack from xlo)
        #pragma unroll
        for (int r = 0; r < 4; r++) {
            if ((unsigned)(h0 + r - 1) < 256u) {
                u16* dst = xr + r * 5160 + (t + 1) * 20;
                #pragma unroll
                for (int g = 0; g < 4; g++) {
                    uint2 lp;
                    lp.x = xlo[r * 8 + g * 2];
                    lp.y = xlo[r * 8 + g * 2 + 1];
                    *(uint2*)&dst[g * 4] = lp;
                }
            }
        }
        __syncthreads();
        // ---- lo-MFMA: Wh*Xl; prefetch+split next chunk (xhi/xlo free now)
        if (ch < 7) load_split_match(feat, b, ch + 1, h0, t, xhi, xlo);
        #pragma unroll
        for (int kw = 0; kw < 3; kw++) {
            #pragma unroll
            for (int ks = 0; ks < 3; ks++) {
                int k0 = ks * 16 + kg;
                s8v ah0 = ld8(&wl[(kw * 64 + nn) * 52 + k0]);
                s8v ah1 = ld8(&wl[(kw * 64 + 32 + nn) * 52 + k0]);
                #pragma unroll
                for (int o = 0; o < 2; o++) {
                    #pragma unroll
                    for (int pt = 0; pt < 2; pt++) {
                        s8v xf = ld8(&xr[(ks + o) * 5160
                                         + ((wv * 2 + pt) * 32 + nn + kw) * 20 + kg]);
                        acc[o][pt][0] = __builtin_amdgcn_mfma_f32_32x32x16_bf16(ah0, xf, acc[o][pt][0], 0, 0, 0);
                        acc[o][pt][1] = __builtin_amdgcn_mfma_f32_32x32x16_bf16(ah1, xf, acc[o][pt][1], 0, 0, 0);
                    }
                }
            }
        }
        __syncthreads();
    }

    #pragma unroll
    for (int o = 0; o < 2; o++) {
        int h = h0 + o;
        #pragma unroll
        for (int pt = 0; pt < 2; pt++) {
            int px = (wv * 2 + pt) * 32 + nn;
            #pragma unroll
            for (int s = 0; s < 2; s++) {
                #pragma unroll
                for (int r = 0; r < 16; r++) {
                    int cm = s * 32 + (r & 3) + 8 * (r >> 2) + 4 * (l >> 5);
                    float sg = 1.f / (1.f + __expf(-acc[o][pt][s][r]));
                    if (cm < 30)
                        out_all[(((size_t)b * 30 + cm) * 256 + h) * 256 + px] = sg;
                    else if (cm < 62)
                        out_anom[(((size_t)b * 32 + cm - 30) * 256 + h) * 256 + px] = sg;
                }
            }
        }
    }
}

// ---------------- heads MFMA: 190->68 1x1, 3-term split ----------------
__device__ __forceinline__ void load_x_heads(const float* __restrict__ fb,
                                             const float* __restrict__ ab,
                                             const float* __restrict__ nb,
                                             int ch, float xv[16]) {
    #pragma unroll
    for (int ci = 0; ci < 16; ci++) {
        int k = ch * 16 + ci;
        float v;
        if (k < 128)      v = fb[(size_t)k << 16];
        else if (k < 158) v = ab[(size_t)(k - 128) << 16];
        else if (k < 190) v = nb[(size_t)(k - 158) << 16];
        else              v = 0.f;
        xv[ci] = v;
    }
}

__global__ __launch_bounds__(256, 3) void k_heads_mf(
    const float* __restrict__ dout, const u16* __restrict__ whl,
    const float* __restrict__ qa1b, const float* __restrict__ qa2w,
    const float* __restrict__ qa2b, const float* __restrict__ clsb,
    float* __restrict__ out)
{
    const int h = blockIdx.x, b = blockIdx.y;
    const int t = threadIdx.x, l = t & 63, wv = t >> 6;
    const int kg = (l >> 5) * 8, nn = l & 31;

    __shared__ __align__(16) u16 xh[256 * 20];    // hi plane, row px, pad 20
    __shared__ __align__(16) u16 xl[256 * 20];    // lo plane
    __shared__ __align__(16) u16 wl2[2 * 1920];   // hi, lo weights for chunk
    __shared__ float lb[69];                      // qa1b[64], clsb[4], qa2b
    __shared__ float lw2[64];                     // qa2w

    if (t < 64) { lb[t] = qa1b[t]; lw2[t] = qa2w[t]; }
    if (t < 4) lb[64 + t] = clsb[t];
    if (t == 0) lb[68] = qa2b[0];

    f16v acc[3][2];
    #pragma unroll
    for (int s = 0; s < 3; s++)
        #pragma unroll
        for (int pt = 0; pt < 2; pt++)
            #pragma unroll
            for (int r = 0; r < 16; r++) acc[s][pt][r] = 0.f;

    const float* fb = dout + O0 + (((size_t)b * 128) << 16) + ((size_t)h << 8) + t;
    const float* ab = dout + O3 + (((size_t)b * 30) << 16) + ((size_t)h << 8) + t;
    const float* nb = dout + O4 + (((size_t)b * 32) << 16) + ((size_t)h << 8) + t;

    float xv[16];
    load_x_heads(fb, ab, nb, 0, xv);

    #pragma unroll
    for (int ch = 0; ch < 12; ch++) {
        {
            const int4* src = (const int4*)(whl + (size_t)ch * 3840);
            for (int i = t; i < 480; i += 256) ((int4*)wl2)[i] = src[i];
        }
        #pragma unroll
        for (int g = 0; g < 4; g++) {
            int i0 = g * 4;
            u16 h0 = f2u(xv[i0 + 0]), h1 = f2u(xv[i0 + 1]);
            u16 h2 = f2u(xv[i0 + 2]), h3 = f2u(xv[i0 + 3]);
            uint2 hp, lp;
            hp.x = (unsigned)h0 | ((unsigned)h1 << 16);
            hp.y = (unsigned)h2 | ((unsigned)h3 << 16);
            lp.x = (unsigned)f2u(xv[i0 + 0] - u2f(h0))
                 | ((unsigned)f2u(xv[i0 + 1] - u2f(h1)) << 16);
            lp.y = (unsigned)f2u(xv[i0 + 2] - u2f(h2))
                 | ((unsigned)f2u(xv[i0 + 3] - u2f(h3)) << 16);
            *(uint2*)&xh[t * 20 + i0] = hp;
            *(uint2*)&xl[t * 20 + i0] = lp;
        }
        __syncthreads();
        if (ch < 11) load_x_heads(fb, ab, nb, ch + 1, xv);   // overlap with MFMA
        s8v xfh[2], xfl[2];
        #pragma unroll
        for (int pt = 0; pt < 2; pt++) {
            int row = (wv * 2 + pt) * 32 + nn;
            xfh[pt] = ld8(&xh[row * 20 + kg]);
            xfl[pt] = ld8(&xl[row * 20 + kg]);
        }
        #pragma unroll
        for (int s = 0; s < 3; s++) {
            s8v awh = ld8(&wl2[(s * 32 + nn) * 20 + kg]);
            s8v awl = ld8(&wl2[1920 + (s * 32 + nn) * 20 + kg]);
            #pragma unroll
            for (int pt = 0; pt < 2; pt++) {
                acc[s][pt] = __builtin_amdgcn_mfma_f32_32x32x16_bf16(awh, xfh[pt], acc[s][pt], 0, 0, 0);
                acc[s][pt] = __builtin_amdgcn_mfma_f32_32x32x16_bf16(awl, xfh[pt], acc[s][pt], 0, 0, 0);
                acc[s][pt] = __builtin_amdgcn_mfma_f32_32x32x16_bf16(awh, xfl[pt], acc[s][pt], 0, 0, 0);
            }
        }
        __syncthreads();
    }

    // ---- epilogue: qa dot + sigmoid, cls softmax/sigmoid ----
    const int hi = l >> 5;
    #pragma unroll
    for (int pt = 0; pt < 2; pt++) {
        float qa_part = 0.f;
        #pragma unroll
        for (int m = 0; m < 2; m++)
            #pragma unroll
            for (int r = 0; r < 16; r++) {
                int row = m * 32 + (r & 3) + 8 * (r >> 2) + 4 * hi;
                float v = acc[m][pt][r] + lb[row];
                qa_part += fmaxf(v, 0.f) * lw2[row];
            }
        qa_part += __shfl_xor(qa_part, 32, 64);
        if (hi == 0) {
            int px = (wv * 2 + pt) * 32 + nn;
            size_t hw = (size_t)h * 256 + px;
            float quality = 1.f / (1.f + __expf(-(qa_part + lb[68])));
            float c0 = acc[2][pt][0] + lb[64];
            float c1 = acc[2][pt][1] + lb[65];
            float c2 = acc[2][pt][2] + lb[66];
            float c3 = acc[2][pt][3] + lb[67];
            float m0 = fmaxf(c0, fmaxf(c1, c2));
            float e0 = __expf(c0 - m0), e1 = __expf(c1 - m0), e2 = __expf(c2 - m0);
            float inv = 1.f / (e0 + e1 + e2);
            out[O1 + ((size_t)b * 3 + 0) * HWX + hw] = c0;
            out[O1 + ((size_t)b * 3 + 1) * HWX + hw] = c1;
            out[O1 + ((size_t)b * 3 + 2) * HWX + hw] = c2;
            out[O2 + (size_t)b * HWX + hw] = c3;
            out[O5 + (size_t)b * HWX + hw] = quality;
            out[O6 + ((size_t)b * 3 + 0) * HWX + hw] = e0 * inv;
            out[O6 + ((size_t)b * 3 + 1) * HWX + hw] = e1 * inv;
            out[O6 + ((size_t)b * 3 + 2) * HWX + hw] = e2 * inv;
            out[O7 + (size_t)b * HWX + hw] = 1.f / (1.f + __expf(-c3));
        }
    }
}

extern "C" void kernel_launch(void* const* d_in, const int* in_sizes, int n_in,
                              void* d_out, int out_size, void* d_ws, size_t ws_size,
                              hipStream_t stream) {
    (void)in_sizes; (void)n_in; (void)out_size; (void)ws_size;
    const float* x    = (const float*)d_in[0];
    const float* w1   = (const float*)d_in[1];
    const float* b1   = (const float*)d_in[2];
    const float* g1   = (const float*)d_in[3];
    const float* be1  = (const float*)d_in[4];
    const float* w2   = (const float*)d_in[5];
    const float* b2   = (const float*)d_in[6];
    const float* g2   = (const float*)d_in[7];
    const float* be2  = (const float*)d_in[8];
    const float* core = (const float*)d_in[9];
    const float* clad = (const float*)d_in[10];
    const float* ferr = (const float*)d_in[11];
    const float* anom = (const float*)d_in[12];
    const float* qa1w = (const float*)d_in[13];
    const float* qa1b = (const float*)d_in[14];
    const float* qa2w = (const float*)d_in[15];
    const float* qa2b = (const float*)d_in[16];
    const float* clsw = (const float*)d_in[17];
    const float* clsb = (const float*)d_in[18];

    char* ws = (char*)d_ws;
    float* stats = (float*)ws;
    float* s1 = stats + 0;
    float* q1 = stats + 64;
    float* s2 = stats + 128;
    float* q2 = stats + 256;
    float* sc1 = stats + 384;
    float* sh1 = stats + 448;
    u16*   hraw   = (u16*)(ws + 4096);                // 33,554,432 B
    float* wcat   = (float*)(ws + 33558528ull);       // 285,696 B (dead after k_prep_w -> reused as whl)
    u16*   wtile2 = (u16*)(ws + 33844224ull);         // 79,872*2 B
    u16*   wtile  = (u16*)(ws + 34004224ull);         // 159,744*2 B
    u16*   whl    = (u16*)wcat;                       // 92,160 B, alias (safe: after k_prep_w)
    float* dout = (float*)d_out;

    hipMemsetAsync(stats, 0, 384 * sizeof(float), stream);
    hipMemcpyAsync(wcat,             core, 10 * 1152 * 4, hipMemcpyDeviceToDevice, stream);
    hipMemcpyAsync(wcat + 10 * 1152, clad, 10 * 1152 * 4, hipMemcpyDeviceToDevice, stream);
    hipMemcpyAsync(wcat + 20 * 1152, ferr, 10 * 1152 * 4, hipMemcpyDeviceToDevice, stream);
    hipMemcpyAsync(wcat + 30 * 1152, anom, 32 * 1152 * 4, hipMemcpyDeviceToDevice, stream);

    dim3 blk(256);
    k_prep_w2<<<312, blk, 0, stream>>>(w2, wtile2);
    k_prep_w<<<624, blk, 0, stream>>>(wcat, wtile);
    k_prep_wh<<<180, blk, 0, stream>>>(qa1w, clsw, whl);   // overwrites wcat (dead)

    k_conv1<<<dim3(256, 2, 4), blk, 0, stream>>>(x, w1, b1, hraw, s1, q1);
    k_finalize<<<1, 128, 0, stream>>>(s1, q1, g1, be1, sc1, sh1, 64);
    k_bnrelu_h<<<16384, blk, 0, stream>>>((ushort4*)hraw, sc1, sh1);

    k_conv2_mf<<<dim3(256, 4), blk, 0, stream>>>(hraw, wtile2, b2, dout + O0, s2, q2);
    k_bnrelu<<<32768, blk, 0, stream>>>((float4*)(dout + O0), s2, q2, g2, be2, 128);

    k_match_mf<<<dim3(128, 4), blk, 0, stream>>>(dout + O0, wtile, dout + O3, dout + O4);
    k_heads_mf<<<dim3(256, 4), blk, 0, stream>>>(dout, whl, qa1b, qa2w, qa2b, clsb, dout);
}

// Round 8
// 684.177 us; speedup vs baseline: 1.0764x; 1.0764x over previous
//
#include <hip/hip_runtime.h>
#include <hip/hip_bf16.h>

typedef unsigned short u16;
typedef __attribute__((ext_vector_type(8)))  short s8v;
typedef __attribute__((ext_vector_type(4)))  short s4v;
typedef __attribute__((ext_vector_type(16))) float f16v;

#define HWX 65536
#define EPSV 1e-5f

// d_out element offsets (fp32), concatenated tuple order
#define O0 0u
#define O1 33554432u
#define O2 34340864u
#define O3 34603008u
#define O4 42467328u
#define O5 50855936u
#define O6 51118080u
#define O7 51904512u

__device__ __forceinline__ float u2f(u16 u) {
    union { unsigned int i; float f; } v; v.i = ((unsigned int)u) << 16; return v.f;
}
__device__ __forceinline__ u16 f2u(float f) {
    __hip_bfloat16 h = __float2bfloat16(f);
    return *reinterpret_cast<u16*>(&h);
}
__device__ __forceinline__ s8v ld8(const u16* p) {
    union { s8v v; s4v h[2]; } r;
    r.h[0] = *(const s4v*)p;
    r.h[1] = *(const s4v*)(p + 4);
    return r.v;
}

#define PHYS(i) ((i) + ((i) >> 5))

// ---------------- conv1: 3->64 fp32 direct (swizzled LDS), bf16 out + stats --
__global__ __launch_bounds__(256) void k_conv1(const float* __restrict__ x,
                                               const float* __restrict__ w,
                                               const float* __restrict__ bias,
                                               u16* __restrict__ out,
                                               float* __restrict__ ssum,
                                               float* __restrict__ sqsum) {
    const int h = blockIdx.x, cb = blockIdx.y, b = blockIdx.z;
    const int t = threadIdx.x;
    const int pg = t & 31, cg = t >> 5;
    const int px0 = pg * 8, c0 = cg * 4;
    const int cbase = cb * 32;

    __shared__ float xs[3][3][266];
    __shared__ float wl[27 * 33];

    float acc[4][8];
    #pragma unroll
    for (int c = 0; c < 4; c++) {
        float bv = bias[cbase + c0 + c];
        #pragma unroll
        for (int p = 0; p < 8; p++) acc[c][p] = bv;
    }

    for (int idx = t; idx < 3 * 768; idx += 256) {
        int ci = idx / 768, rem = idx - ci * 768;
        int r = rem >> 8, px = rem & 255;
        int hh = h + r - 1;
        float v = 0.f;
        if ((unsigned)hh < 256u)
            v = x[((size_t)(b * 3 + ci) * 256 + hh) * 256 + px];
        xs[ci][r][PHYS(1 + px)] = v;
    }
    if (t < 18) {
        int ci = t / 6, rr = t - ci * 6;
        xs[ci][rr >> 1][(rr & 1) ? PHYS(257) : 0] = 0.f;
    }
    for (int idx = t; idx < 27 * 32; idx += 256) {
        int co = idx / 27, rem = idx - co * 27;
        wl[rem * 33 + co] = w[(cbase + co) * 27 + rem];
    }
    __syncthreads();

    for (int ci = 0; ci < 3; ci++) {
        #pragma unroll
        for (int kh = 0; kh < 3; kh++) {
            float xv[10];
            #pragma unroll
            for (int j = 0; j < 10; j++) xv[j] = xs[ci][kh][PHYS(px0 + j)];
            float wv[3][4];
            #pragma unroll
            for (int kw = 0; kw < 3; kw++)
                #pragma unroll
                for (int c = 0; c < 4; c++)
                    wv[kw][c] = wl[(ci * 9 + kh * 3 + kw) * 33 + c0 + c];
            #pragma unroll
            for (int c = 0; c < 4; c++)
                #pragma unroll
                for (int p = 0; p < 8; p++)
                    acc[c][p] += xv[p] * wv[0][c] + xv[p + 1] * wv[1][c]
                               + xv[p + 2] * wv[2][c];
        }
    }

    #pragma unroll
    for (int c = 0; c < 4; c++) {
        int cm = cbase + c0 + c;
        u16* op = out + (((size_t)(b * 64 + cm) * 256 + h) * 256 + px0);
        #pragma unroll
        for (int p = 0; p < 8; p++) op[p] = f2u(acc[c][p]);
    }

    __syncthreads();
    float* red = &xs[0][0][0];
    #pragma unroll
    for (int c = 0; c < 4; c++) {
        float sv = 0.f, qv = 0.f;
        #pragma unroll
        for (int p = 0; p < 8; p++) { sv += acc[c][p]; qv += acc[c][p] * acc[c][p]; }
        red[(c0 + c) * 33 + pg] = sv;
        red[1056 + (c0 + c) * 33 + pg] = qv;
    }
    __syncthreads();
    if (t < 64) {
        int co = t & 31, v = t >> 5;
        const float* base = red + v * 1056 + co * 33;
        float sum = 0.f;
        #pragma unroll
        for (int i = 0; i < 32; i++) sum += base[i];
        atomicAdd((v ? sqsum : ssum) + cbase + co, sum);
    }
}

// ---------------- finalize BN1 ----------------
__global__ void k_finalize(const float* __restrict__ s, const float* __restrict__ q,
                           const float* __restrict__ g, const float* __restrict__ be,
                           float* __restrict__ sc, float* __restrict__ sh, int C) {
    int c = threadIdx.x;
    if (c >= C) return;
    const float invN = 1.f / 262144.f;
    float m = s[c] * invN;
    float v = fmaxf(q[c] * invN - m * m, 0.f);
    float scale = g[c] * rsqrtf(v + EPSV);
    sc[c] = scale;
    sh[c] = be[c] - m * scale;
}

// ---------------- BN+ReLU on bf16 buffer (in place) ----------------
__global__ __launch_bounds__(256) void k_bnrelu_h(ushort4* __restrict__ buf,
                                                  const float* __restrict__ sc,
                                                  const float* __restrict__ sh) {
    size_t i = (size_t)blockIdx.x * 256 + threadIdx.x;
    int c = (int)(i >> 14) & 63;
    float s = sc[c], h0 = sh[c];
    ushort4 r = buf[i];
    ushort4 o;
    o.x = f2u(fmaxf(u2f(r.x) * s + h0, 0.f));
    o.y = f2u(fmaxf(u2f(r.y) * s + h0, 0.f));
    o.z = f2u(fmaxf(u2f(r.z) * s + h0, 0.f));
    o.w = f2u(fmaxf(u2f(r.w) * s + h0, 0.f));
    buf[i] = o;
}

// ---------------- BN+ReLU fp32 (features, in place; finalize fused) ---------
__global__ __launch_bounds__(256) void k_bnrelu(float4* __restrict__ buf,
                                                const float* __restrict__ s,
                                                const float* __restrict__ q,
                                                const float* __restrict__ g,
                                                const float* __restrict__ be, int C) {
    size_t i = (size_t)blockIdx.x * 256 + threadIdx.x;
    int c = (int)(i >> 14) % C;
    const float invN = 1.f / 262144.f;
    float m = s[c] * invN;
    float var = fmaxf(q[c] * invN - m * m, 0.f);
    float sc = g[c] * rsqrtf(var + EPSV);
    float sh = be[c] - m * sc;
    float4 r = buf[i];
    float4 o;
    o.x = fmaxf(r.x * sc + sh, 0.f);
    o.y = fmaxf(r.y * sc + sh, 0.f);
    o.z = fmaxf(r.z * sc + sh, 0.f);
    o.w = fmaxf(r.w * sc + sh, 0.f);
    buf[i] = o;
}

// ---------------- per-channel stats over raw conv2 out ----------------
__global__ __launch_bounds__(256) void k_stats(const float* __restrict__ raw,
                                               float* __restrict__ ssum,
                                               float* __restrict__ sqsum) {
    const int co = blockIdx.x, seg = blockIdx.y;
    const int t = threadIdx.x;
    __shared__ float red[8];
    float s = 0.f, q = 0.f;
    for (int b = 0; b < 4; b++) {
        const float4* p = (const float4*)(raw + ((size_t)(b * 128 + co) * HWX) + seg * 8192);
        for (int i = t; i < 2048; i += 256) {
            float4 v = p[i];
            s += v.x + v.y + v.z + v.w;
            q += v.x * v.x + v.y * v.y + v.z * v.z + v.w * v.w;
        }
    }
    #pragma unroll
    for (int off = 32; off; off >>= 1) {
        s += __shfl_down(s, off, 64);
        q += __shfl_down(q, off, 64);
    }
    int lane = t & 63, wv = t >> 6;
    if (lane == 0) { red[wv] = s; red[4 + wv] = q; }
    __syncthreads();
    if (t == 0) atomicAdd(&ssum[co], red[0] + red[1] + red[2] + red[3]);
    else if (t == 1) atomicAdd(&sqsum[co], red[4] + red[5] + red[6] + red[7]);
}

// ---------------- weight pre-tiling ----------------
// match: wtile[(ch*2+plane)*9984 + (kw*64+co)*52 + kh*16+cil], ch=ci/16, 8 chunks
__global__ void k_prep_w(const float* __restrict__ wcat, u16* __restrict__ wtile) {
    int i = blockIdx.x * 256 + threadIdx.x;
    if (i >= 159744) return;
    int ch = i / 19968, rem = i - ch * 19968;
    int pl = rem / 9984; rem -= pl * 9984;
    int kwco = rem / 52, k = rem - kwco * 52;
    int kw = kwco >> 6, co = kwco & 63;
    u16 v = 0;
    if (k < 48 && co < 62) {
        int kh = k >> 4, ci = ch * 16 + (k & 15);
        float f = wcat[(size_t)co * 1152 + ci * 9 + kh * 3 + kw];
        u16 hv = f2u(f);
        v = pl ? f2u(f - u2f(hv)) : hv;
    }
    wtile[i] = v;
}
// conv2: wtile2[ch*19968 + (kw*128+co)*52 + kh*16+cil], 4 chunks of 16 ci
__global__ void k_prep_w2(const float* __restrict__ w2, u16* __restrict__ wtile2) {
    int i = blockIdx.x * 256 + threadIdx.x;
    if (i >= 79872) return;                 // 4 * 3*128*52
    int ch = i / 19968, rem = i - ch * 19968;
    int kwco = rem / 52, k = rem - kwco * 52;
    int kw = kwco >> 7, co = kwco & 127;
    u16 v = 0;
    if (k < 48) {
        int kh = k >> 4, ci = ch * 16 + (k & 15);
        v = f2u(w2[((size_t)co * 64 + ci) * 9 + kh * 3 + kw]);
    }
    wtile2[i] = v;
}
// heads: whl[ch*3840 + pl*1920 + co*20 + kloc], 12 chunks of 16 k, 96 rows (68 used)
__global__ void k_prep_wh(const float* __restrict__ qa1w, const float* __restrict__ clsw,
                          u16* __restrict__ whl) {
    int i = blockIdx.x * 256 + threadIdx.x;
    if (i >= 46080) return;
    int ch = i / 3840, rem = i - ch * 3840;
    int pl = rem / 1920; rem -= pl * 1920;
    int co = rem / 20, kloc = rem - co * 20;
    u16 v = 0;
    int k = ch * 16 + kloc;
    if (kloc < 16 && k < 190 && co < 68) {
        float f = (co < 64) ? qa1w[co * 190 + k] : clsw[(co - 64) * 190 + k];
        u16 hv = f2u(f);
        v = pl ? f2u(f - u2f(hv)) : hv;
    }
    whl[i] = v;
}

// ---- x prefetch helpers ----------------------------------------------------
__device__ __forceinline__ void load_x_c2(const u16* __restrict__ hb, int b, int ch,
                                          int h, int t, unsigned xp[24]) {
    #pragma unroll
    for (int r = 0; r < 3; r++) {
        int hh = h + r - 1;
        bool vr = (unsigned)hh < 256u;
        if (vr) {
            const u16* base = hb + ((size_t)(b * 64 + ch * 16) << 16)
                            + ((size_t)hh << 8) + t;
            #pragma unroll
            for (int ci = 0; ci < 16; ci += 2) {
                unsigned a = base[(size_t)ci << 16];
                unsigned c = base[(size_t)(ci + 1) << 16];
                xp[(r * 16 + ci) >> 1] = a | (c << 16);
            }
        } else {
            #pragma unroll
            for (int ci = 0; ci < 16; ci += 2) xp[(r * 16 + ci) >> 1] = 0u;
        }
    }
}

// h-tiled match: load 4 input rows (h0-1..h0+2) and split to packed bf16
// hi/lo planes at load time -> 32+32 u32 live regs instead of 64 f32.
__device__ __forceinline__ void load_split_match(const float* __restrict__ feat,
                                                 int b, int ch, int h0, int t,
                                                 unsigned xhi[32], unsigned xlo[32]) {
    #pragma unroll
    for (int r = 0; r < 4; r++) {
        int hh = h0 + r - 1;
        if ((unsigned)hh < 256u) {          // block-uniform branch
            const float* base = feat + ((size_t)(b * 128 + ch * 16) << 16)
                              + ((size_t)hh << 8) + t;
            float v[16];
            #pragma unroll
            for (int ci = 0; ci < 16; ci++)
                v[ci] = base[(size_t)ci << 16];
            #pragma unroll
            for (int ci = 0; ci < 16; ci += 2) {
                u16 ha = f2u(v[ci]), hb2 = f2u(v[ci + 1]);
                unsigned la = f2u(v[ci] - u2f(ha));
                unsigned lb = f2u(v[ci + 1] - u2f(hb2));
                xhi[(r * 16 + ci) >> 1] = (unsigned)ha | ((unsigned)hb2 << 16);
                xlo[(r * 16 + ci) >> 1] = la | (lb << 16);
            }
        }
    }
}

// ---------------- conv2 MFMA: 64->128, bf16 in, fp32 raw out ----------------
__global__ __launch_bounds__(256, 2) void k_conv2_mf(
    const u16* __restrict__ hb, const u16* __restrict__ wtile2,
    const float* __restrict__ bias, float* __restrict__ out)
{
    const int h = blockIdx.x, b = blockIdx.y;
    const int t = threadIdx.x, l = t & 63, wv = t >> 6;
    const int kg = (l >> 5) * 8, nn = l & 31;

    __shared__ __align__(16) u16 xs[258 * 52];
    __shared__ __align__(16) u16 wl[3 * 128 * 52];

    f16v acc[2][4];
    #pragma unroll
    for (int pt = 0; pt < 2; pt++)
        #pragma unroll
        for (int s = 0; s < 4; s++)
            #pragma unroll
            for (int r = 0; r < 16; r++) acc[pt][s][r] = 0.f;

    // one-time zero fill (pads + out-of-range rows persist as 0)
    for (int i = t; i < 258 * 52 / 4; i += 256)
        ((ushort4*)xs)[i] = ushort4{0, 0, 0, 0};
    __syncthreads();

    unsigned xp[24];
    load_x_c2(hb, b, 0, h, t, xp);

    for (int ch = 0; ch < 4; ch++) {
        {
            const int4* src = (const int4*)(wtile2 + (size_t)ch * 19968);
            for (int i = t; i < 2496; i += 256) ((int4*)wl)[i] = src[i];
        }
        #pragma unroll
        for (int r = 0; r < 3; r++) {
            if ((unsigned)(h + r - 1) < 256u) {
                #pragma unroll
                for (int g = 0; g < 4; g++) {
                    int i0 = r * 16 + g * 4;
                    uint2 hp;
                    hp.x = xp[i0 >> 1];
                    hp.y = xp[(i0 >> 1) + 1];
                    *(uint2*)&xs[(size_t)(t + 1) * 52 + i0] = hp;
                }
            }
        }
        __syncthreads();
        if (ch < 3) load_x_c2(hb, b, ch + 1, h, t, xp);   // overlap with MFMA
        #pragma unroll
        for (int kw = 0; kw < 3; kw++) {
            #pragma unroll
            for (int ks = 0; ks < 3; ks++) {
                int k0 = ks * 16 + kg;
                s8v af[4], bf[2];
                #pragma unroll
                for (int s = 0; s < 4; s++)
                    af[s] = ld8(&wl[(kw * 128 + s * 32 + nn) * 52 + k0]);
                #pragma unroll
                for (int pt = 0; pt < 2; pt++)
                    bf[pt] = ld8(&xs[((wv * 2 + pt) * 32 + nn + kw) * 52 + k0]);
                #pragma unroll
                for (int pt = 0; pt < 2; pt++)
                    #pragma unroll
                    for (int s = 0; s < 4; s++)
                        acc[pt][s] = __builtin_amdgcn_mfma_f32_32x32x16_bf16(
                            af[s], bf[pt], acc[pt][s], 0, 0, 0);
            }
        }
        __syncthreads();
    }

    #pragma unroll
    for (int pt = 0; pt < 2; pt++) {
        int px = (wv * 2 + pt) * 32 + nn;
        #pragma unroll
        for (int s = 0; s < 4; s++) {
            #pragma unroll
            for (int r = 0; r < 16; r++) {
                int co = s * 32 + (r & 3) + 8 * (r >> 2) + 4 * (l >> 5);
                out[(((size_t)b * 128 + co) * 256 + h) * 256 + px] = acc[pt][s][r] + bias[co];
            }
        }
    }
}

// ---------------- match MFMA: 128->62, 3-term split, h-tiled x2 -------------
__global__ __launch_bounds__(256, 2) void k_match_mf(
    const float* __restrict__ feat, const u16* __restrict__ wtile,
    float* __restrict__ out_all, float* __restrict__ out_anom)
{
    const int h0 = blockIdx.x * 2, b = blockIdx.y;
    const int t = threadIdx.x, l = t & 63, wv = t >> 6;
    const int kg = (l >> 5) * 8, nn = l & 31;

    __shared__ __align__(16) u16 xr[4 * 258 * 20];   // 41,280 B (hi then lo, per chunk)
    __shared__ __align__(16) u16 wl[2 * 9984];       // 39,936 B (hi, lo weights for chunk)

    f16v acc[2][2][2];   // [o][pt][s]
    #pragma unroll
    for (int o = 0; o < 2; o++)
        #pragma unroll
        for (int pt = 0; pt < 2; pt++)
            #pragma unroll
            for (int s = 0; s < 2; s++)
                #pragma unroll
                for (int r = 0; r < 16; r++) acc[o][pt][s][r] = 0.f;

    // one-time zero fill (px halos + out-of-range input rows persist as 0)
    for (int i = t; i < 4 * 258 * 20 / 4; i += 256)
        ((ushort4*)xr)[i] = ushort4{0, 0, 0, 0};
    __syncthreads();

    unsigned xhi[32], xlo[32];
    load_split_match(feat, b, 0, h0, t, xhi, xlo);

    for (int ch = 0; ch < 8; ch++) {
        // weights: both planes contiguous, 2496 int4
        {
            const int4* src = (const int4*)(wtile + (size_t)ch * 2 * 9984);
            for (int i = t; i < 2496; i += 256) ((int4*)wl)[i] = src[i];
        }
        // ---- hi planes write (packed b64, px slot t+1)
        #pragma unroll
        for (int r = 0; r < 4; r++) {
            if ((unsigned)(h0 + r - 1) < 256u) {       // block-uniform branch
                u16* dst = xr + r * 5160 + (t + 1) * 20;
                #pragma unroll
                for (int g = 0; g < 4; g++) {
                    uint2 hp;
                    hp.x = xhi[r * 8 + g * 2];
                    hp.y = xhi[r * 8 + g * 2 + 1];
                    *(uint2*)&dst[g * 4] = hp;
                }
            }
        }
        __syncthreads();
        // ---- hi-MFMA: Wh*Xh + Wl*Xh for both output rows
        #pragma unroll
        for (int kw = 0; kw < 3; kw++) {
            #pragma unroll
            for (int ks = 0; ks < 3; ks++) {
                int k0 = ks * 16 + kg;
                s8v ah0 = ld8(&wl[(kw * 64 + nn) * 52 + k0]);
                s8v ah1 = ld8(&wl[(kw * 64 + 32 + nn) * 52 + k0]);
                s8v al0 = ld8(&wl[9984 + (kw * 64 + nn) * 52 + k0]);
                s8v al1 = ld8(&wl[9984 + (kw * 64 + 32 + nn) * 52 + k0]);
                #pragma unroll
                for (int o = 0; o < 2; o++) {
                    #pragma unroll
                    for (int pt = 0; pt < 2; pt++) {
                        s8v xf = ld8(&xr[(ks + o) * 5160
                                         + ((wv * 2 + pt) * 32 + nn + kw) * 20 + kg]);
                        acc[o][pt][0] = __builtin_amdgcn_mfma_f32_32x32x16_bf16(ah0, xf, acc[o][pt][0], 0, 0, 0);
                        acc[o][pt][0] = __builtin_amdgcn_mfma_f32_32x32x16_bf16(al0, xf, acc[o][pt][0], 0, 0, 0);
                        acc[o][pt][1] = __builtin_amdgcn_mfma_f32_32x32x16_bf16(ah1, xf, acc[o][pt][1], 0, 0, 0);
                        acc[o][pt][1] = __builtin_amdgcn_mfma_f32_32x32x16_bf16(al1, xf, acc[o][pt][1], 0, 0, 0);
                    }
                }
            }
        }
        __syncthreads();
        // ---- lo planes write (pure unpack from xlo)
        #pragma unroll
        for (int r = 0; r < 4; r++) {
            if ((unsigned)(h0 + r - 1) < 256u) {
                u16* dst = xr + r * 5160 + (t + 1) * 20;
                #pragma unroll
                for (int g = 0; g < 4; g++) {
                    uint2 lp;
                    lp.x = xlo[r * 8 + g * 2];
                    lp.y = xlo[r * 8 + g * 2 + 1];
                    *(uint2*)&dst[g * 4] = lp;
                }
            }
        }
        __syncthreads();
        // ---- lo-MFMA: Wh*Xl; prefetch+split next chunk (xhi/xlo free now)
        if (ch < 7) load_split_match(feat, b, ch + 1, h0, t, xhi, xlo);
        #pragma unroll
        for (int kw = 0; kw < 3; kw++) {
            #pragma unroll
            for (int ks = 0; ks < 3; ks++) {
                int k0 = ks * 16 + kg;
                s8v ah0 = ld8(&wl[(kw * 64 + nn) * 52 + k0]);
                s8v ah1 = ld8(&wl[(kw * 64 + 32 + nn) * 52 + k0]);
                #pragma unroll
                for (int o = 0; o < 2; o++) {
                    #pragma unroll
                    for (int pt = 0; pt < 2; pt++) {
                        s8v xf = ld8(&xr[(ks + o) * 5160
                                         + ((wv * 2 + pt) * 32 + nn + kw) * 20 + kg]);
                        acc[o][pt][0] = __builtin_amdgcn_mfma_f32_32x32x16_bf16(ah0, xf, acc[o][pt][0], 0, 0, 0);
                        acc[o][pt][1] = __builtin_amdgcn_mfma_f32_32x32x16_bf16(ah1, xf, acc[o][pt][1], 0, 0, 0);
                    }
                }
            }
        }
        __syncthreads();
    }

    #pragma unroll
    for (int o = 0; o < 2; o++) {
        int h = h0 + o;
        #pragma unroll
        for (int pt = 0; pt < 2; pt++) {
            int px = (wv * 2 + pt) * 32 + nn;
            #pragma unroll
            for (int s = 0; s < 2; s++) {
                #pragma unroll
                for (int r = 0; r < 16; r++) {
                    int cm = s * 32 + (r & 3) + 8 * (r >> 2) + 4 * (l >> 5);
                    float sg = 1.f / (1.f + __expf(-acc[o][pt][s][r]));
                    if (cm < 30)
                        out_all[(((size_t)b * 30 + cm) * 256 + h) * 256 + px] = sg;
                    else if (cm < 62)
                        out_anom[(((size_t)b * 32 + cm - 30) * 256 + h) * 256 + px] = sg;
                }
            }
        }
    }
}

// ---------------- heads MFMA: 190->68 1x1, 3-term split ----------------
__device__ __forceinline__ void load_x_heads(const float* __restrict__ fb,
                                             const float* __restrict__ ab,
                                             const float* __restrict__ nb,
                                             int ch, float xv[16]) {
    #pragma unroll
    for (int ci = 0; ci < 16; ci++) {
        int k = ch * 16 + ci;
        float v;
        if (k < 128)      v = fb[(size_t)k << 16];
        else if (k < 158) v = ab[(size_t)(k - 128) << 16];
        else if (k < 190) v = nb[(size_t)(k - 158) << 16];
        else              v = 0.f;
        xv[ci] = v;
    }
}

__global__ __launch_bounds__(256, 2) void k_heads_mf(
    const float* __restrict__ dout, const u16* __restrict__ whl,
    const float* __restrict__ qa1b, const float* __restrict__ qa2w,
    const float* __restrict__ qa2b, const float* __restrict__ clsb,
    float* __restrict__ out)
{
    const int h = blockIdx.x, b = blockIdx.y;
    const int t = threadIdx.x, l = t & 63, wv = t >> 6;
    const int kg = (l >> 5) * 8, nn = l & 31;

    __shared__ __align__(16) u16 xh[256 * 20];    // hi plane, row px, pad 20
    __shared__ __align__(16) u16 xl[256 * 20];    // lo plane
    __shared__ __align__(16) u16 wl2[2 * 1920];   // hi, lo weights for chunk
    __shared__ float lb[69];                      // qa1b[64], clsb[4], qa2b
    __shared__ float lw2[64];                     // qa2w

    if (t < 64) { lb[t] = qa1b[t]; lw2[t] = qa2w[t]; }
    if (t < 4) lb[64 + t] = clsb[t];
    if (t == 0) lb[68] = qa2b[0];

    f16v acc[3][2];
    #pragma unroll
    for (int s = 0; s < 3; s++)
        #pragma unroll
        for (int pt = 0; pt < 2; pt++)
            #pragma unroll
            for (int r = 0; r < 16; r++) acc[s][pt][r] = 0.f;

    const float* fb = dout + O0 + (((size_t)b * 128) << 16) + ((size_t)h << 8) + t;
    const float* ab = dout + O3 + (((size_t)b * 30) << 16) + ((size_t)h << 8) + t;
    const float* nb = dout + O4 + (((size_t)b * 32) << 16) + ((size_t)h << 8) + t;

    float xv[16];
    load_x_heads(fb, ab, nb, 0, xv);

    #pragma unroll
    for (int ch = 0; ch < 12; ch++) {
        {
            const int4* src = (const int4*)(whl + (size_t)ch * 3840);
            for (int i = t; i < 480; i += 256) ((int4*)wl2)[i] = src[i];
        }
        #pragma unroll
        for (int g = 0; g < 4; g++) {
            int i0 = g * 4;
            u16 h0 = f2u(xv[i0 + 0]), h1 = f2u(xv[i0 + 1]);
            u16 h2 = f2u(xv[i0 + 2]), h3 = f2u(xv[i0 + 3]);
            uint2 hp, lp;
            hp.x = (unsigned)h0 | ((unsigned)h1 << 16);
            hp.y = (unsigned)h2 | ((unsigned)h3 << 16);
            lp.x = (unsigned)f2u(xv[i0 + 0] - u2f(h0))
                 | ((unsigned)f2u(xv[i0 + 1] - u2f(h1)) << 16);
            lp.y = (unsigned)f2u(xv[i0 + 2] - u2f(h2))
                 | ((unsigned)f2u(xv[i0 + 3] - u2f(h3)) << 16);
            *(uint2*)&xh[t * 20 + i0] = hp;
            *(uint2*)&xl[t * 20 + i0] = lp;
        }
        __syncthreads();
        if (ch < 11) load_x_heads(fb, ab, nb, ch + 1, xv);   // overlap with MFMA
        s8v xfh[2], xfl[2];
        #pragma unroll
        for (int pt = 0; pt < 2; pt++) {
            int row = (wv * 2 + pt) * 32 + nn;
            xfh[pt] = ld8(&xh[row * 20 + kg]);
            xfl[pt] = ld8(&xl[row * 20 + kg]);
        }
        #pragma unroll
        for (int s = 0; s < 3; s++) {
            s8v awh = ld8(&wl2[(s * 32 + nn) * 20 + kg]);
            s8v awl = ld8(&wl2[1920 + (s * 32 + nn) * 20 + kg]);
            #pragma unroll
            for (int pt = 0; pt < 2; pt++) {
                acc[s][pt] = __builtin_amdgcn_mfma_f32_32x32x16_bf16(awh, xfh[pt], acc[s][pt], 0, 0, 0);
                acc[s][pt] = __builtin_amdgcn_mfma_f32_32x32x16_bf16(awl, xfh[pt], acc[s][pt], 0, 0, 0);
                acc[s][pt] = __builtin_amdgcn_mfma_f32_32x32x16_bf16(awh, xfl[pt], acc[s][pt], 0, 0, 0);
            }
        }
        __syncthreads();
    }

    // ---- epilogue: qa dot + sigmoid, cls softmax/sigmoid ----
    const int hi = l >> 5;
    #pragma unroll
    for (int pt = 0; pt < 2; pt++) {
        float qa_part = 0.f;
        #pragma unroll
        for (int m = 0; m < 2; m++)
            #pragma unroll
            for (int r = 0; r < 16; r++) {
                int row = m * 32 + (r & 3) + 8 * (r >> 2) + 4 * hi;
                float v = acc[m][pt][r] + lb[row];
                qa_part += fmaxf(v, 0.f) * lw2[row];
            }
        qa_part += __shfl_xor(qa_part, 32, 64);
        if (hi == 0) {
            int px = (wv * 2 + pt) * 32 + nn;
            size_t hw = (size_t)h * 256 + px;
            float quality = 1.f / (1.f + __expf(-(qa_part + lb[68])));
            float c0 = acc[2][pt][0] + lb[64];
            float c1 = acc[2][pt][1] + lb[65];
            float c2 = acc[2][pt][2] + lb[66];
            float c3 = acc[2][pt][3] + lb[67];
            float m0 = fmaxf(c0, fmaxf(c1, c2));
            float e0 = __expf(c0 - m0), e1 = __expf(c1 - m0), e2 = __expf(c2 - m0);
            float inv = 1.f / (e0 + e1 + e2);
            out[O1 + ((size_t)b * 3 + 0) * HWX + hw] = c0;
            out[O1 + ((size_t)b * 3 + 1) * HWX + hw] = c1;
            out[O1 + ((size_t)b * 3 + 2) * HWX + hw] = c2;
            out[O2 + (size_t)b * HWX + hw] = c3;
            out[O5 + (size_t)b * HWX + hw] = quality;
            out[O6 + ((size_t)b * 3 + 0) * HWX + hw] = e0 * inv;
            out[O6 + ((size_t)b * 3 + 1) * HWX + hw] = e1 * inv;
            out[O6 + ((size_t)b * 3 + 2) * HWX + hw] = e2 * inv;
            out[O7 + (size_t)b * HWX + hw] = 1.f / (1.f + __expf(-c3));
        }
    }
}

extern "C" void kernel_launch(void* const* d_in, const int* in_sizes, int n_in,
                              void* d_out, int out_size, void* d_ws, size_t ws_size,
                              hipStream_t stream) {
    (void)in_sizes; (void)n_in; (void)out_size; (void)ws_size;
    const float* x    = (const float*)d_in[0];
    const float* w1   = (const float*)d_in[1];
    const float* b1   = (const float*)d_in[2];
    const float* g1   = (const float*)d_in[3];
    const float* be1  = (const float*)d_in[4];
    const float* w2   = (const float*)d_in[5];
    const float* b2   = (const float*)d_in[6];
    const float* g2   = (const float*)d_in[7];
    const float* be2  = (const float*)d_in[8];
    const float* core = (const float*)d_in[9];
    const float* clad = (const float*)d_in[10];
    const float* ferr = (const float*)d_in[11];
    const float* anom = (const float*)d_in[12];
    const float* qa1w = (const float*)d_in[13];
    const float* qa1b = (const float*)d_in[14];
    const float* qa2w = (const float*)d_in[15];
    const float* qa2b = (const float*)d_in[16];
    const float* clsw = (const float*)d_in[17];
    const float* clsb = (const float*)d_in[18];

    char* ws = (char*)d_ws;
    float* stats = (float*)ws;
    float* s1 = stats + 0;
    float* q1 = stats + 64;
    float* s2 = stats + 128;
    float* q2 = stats + 256;
    float* sc1 = stats + 384;
    float* sh1 = stats + 448;
    u16*   hraw   = (u16*)(ws + 4096);                // 33,554,432 B
    float* wcat   = (float*)(ws + 33558528ull);       // 285,696 B (dead after k_prep_w -> reused as whl)
    u16*   wtile2 = (u16*)(ws + 33844224ull);         // 79,872*2 B
    u16*   wtile  = (u16*)(ws + 34004224ull);         // 159,744*2 B
    u16*   whl    = (u16*)wcat;                       // 92,160 B, alias (safe: after k_prep_w)
    float* dout = (float*)d_out;

    hipMemsetAsync(stats, 0, 384 * sizeof(float), stream);
    hipMemcpyAsync(wcat,             core, 10 * 1152 * 4, hipMemcpyDeviceToDevice, stream);
    hipMemcpyAsync(wcat + 10 * 1152, clad, 10 * 1152 * 4, hipMemcpyDeviceToDevice, stream);
    hipMemcpyAsync(wcat + 20 * 1152, ferr, 10 * 1152 * 4, hipMemcpyDeviceToDevice, stream);
    hipMemcpyAsync(wcat + 30 * 1152, anom, 32 * 1152 * 4, hipMemcpyDeviceToDevice, stream);

    dim3 blk(256);
    k_prep_w2<<<312, blk, 0, stream>>>(w2, wtile2);
    k_prep_w<<<624, blk, 0, stream>>>(wcat, wtile);
    k_prep_wh<<<180, blk, 0, stream>>>(qa1w, clsw, whl);   // overwrites wcat (dead)

    k_conv1<<<dim3(256, 2, 4), blk, 0, stream>>>(x, w1, b1, hraw, s1, q1);
    k_finalize<<<1, 128, 0, stream>>>(s1, q1, g1, be1, sc1, sh1, 64);
    k_bnrelu_h<<<16384, blk, 0, stream>>>((ushort4*)hraw, sc1, sh1);

    k_conv2_mf<<<dim3(256, 4), blk, 0, stream>>>(hraw, wtile2, b2, dout + O0);
    k_stats<<<dim3(128, 8), blk, 0, stream>>>(dout + O0, s2, q2);
    k_bnrelu<<<32768, blk, 0, stream>>>((float4*)(dout + O0), s2, q2, g2, be2, 128);

    k_match_mf<<<dim3(128, 4), blk, 0, stream>>>(dout + O0, wtile, dout + O3, dout + O4);
    k_heads_mf<<<dim3(256, 4), blk, 0, stream>>>(dout, whl, qa1b, qa2w, qa2b, clsb, dout);
}

// Round 9
// 599.318 us; speedup vs baseline: 1.2288x; 1.1416x over previous
//
#include <hip/hip_runtime.h>
#include <hip/hip_bf16.h>

typedef unsigned short u16;
typedef __attribute__((ext_vector_type(8)))  short s8v;
typedef __attribute__((ext_vector_type(4)))  short s4v;
typedef __attribute__((ext_vector_type(16))) float f16v;

#define HWX 65536
#define EPSV 1e-5f

// d_out element offsets (fp32), concatenated tuple order
#define O0 0u
#define O1 33554432u
#define O2 34340864u
#define O3 34603008u
#define O4 42467328u
#define O5 50855936u
#define O6 51118080u
#define O7 51904512u

__device__ __forceinline__ float u2f(u16 u) {
    union { unsigned int i; float f; } v; v.i = ((unsigned int)u) << 16; return v.f;
}
__device__ __forceinline__ u16 f2u(float f) {
    __hip_bfloat16 h = __float2bfloat16(f);
    return *reinterpret_cast<u16*>(&h);
}
__device__ __forceinline__ s8v ld8(const u16* p) {
    union { s8v v; s4v h[2]; } r;
    r.h[0] = *(const s4v*)p;
    r.h[1] = *(const s4v*)(p + 4);
    return r.v;
}

#define PHYS(i) ((i) + ((i) >> 5))

// ---------------- conv1: 3->64 fp32 direct (swizzled LDS), bf16 raw out + stats
__global__ __launch_bounds__(256) void k_conv1(const float* __restrict__ x,
                                               const float* __restrict__ w,
                                               const float* __restrict__ bias,
                                               u16* __restrict__ out,
                                               float* __restrict__ ssum,
                                               float* __restrict__ sqsum) {
    const int h = blockIdx.x, cb = blockIdx.y, b = blockIdx.z;
    const int t = threadIdx.x;
    const int pg = t & 31, cg = t >> 5;
    const int px0 = pg * 8, c0 = cg * 4;
    const int cbase = cb * 32;

    __shared__ float xs[3][3][266];
    __shared__ float wl[27 * 33];

    float acc[4][8];
    #pragma unroll
    for (int c = 0; c < 4; c++) {
        float bv = bias[cbase + c0 + c];
        #pragma unroll
        for (int p = 0; p < 8; p++) acc[c][p] = bv;
    }

    for (int idx = t; idx < 3 * 768; idx += 256) {
        int ci = idx / 768, rem = idx - ci * 768;
        int r = rem >> 8, px = rem & 255;
        int hh = h + r - 1;
        float v = 0.f;
        if ((unsigned)hh < 256u)
            v = x[((size_t)(b * 3 + ci) * 256 + hh) * 256 + px];
        xs[ci][r][PHYS(1 + px)] = v;
    }
    if (t < 18) {
        int ci = t / 6, rr = t - ci * 6;
        xs[ci][rr >> 1][(rr & 1) ? PHYS(257) : 0] = 0.f;
    }
    for (int idx = t; idx < 27 * 32; idx += 256) {
        int co = idx / 27, rem = idx - co * 27;
        wl[rem * 33 + co] = w[(cbase + co) * 27 + rem];
    }
    __syncthreads();

    for (int ci = 0; ci < 3; ci++) {
        #pragma unroll
        for (int kh = 0; kh < 3; kh++) {
            float xv[10];
            #pragma unroll
            for (int j = 0; j < 10; j++) xv[j] = xs[ci][kh][PHYS(px0 + j)];
            float wv[3][4];
            #pragma unroll
            for (int kw = 0; kw < 3; kw++)
                #pragma unroll
                for (int c = 0; c < 4; c++)
                    wv[kw][c] = wl[(ci * 9 + kh * 3 + kw) * 33 + c0 + c];
            #pragma unroll
            for (int c = 0; c < 4; c++)
                #pragma unroll
                for (int p = 0; p < 8; p++)
                    acc[c][p] += xv[p] * wv[0][c] + xv[p + 1] * wv[1][c]
                               + xv[p + 2] * wv[2][c];
        }
    }

    #pragma unroll
    for (int c = 0; c < 4; c++) {
        int cm = cbase + c0 + c;
        u16* op = out + (((size_t)(b * 64 + cm) * 256 + h) * 256 + px0);
        #pragma unroll
        for (int p = 0; p < 8; p++) op[p] = f2u(acc[c][p]);
    }

    __syncthreads();
    float* red = &xs[0][0][0];
    #pragma unroll
    for (int c = 0; c < 4; c++) {
        float sv = 0.f, qv = 0.f;
        #pragma unroll
        for (int p = 0; p < 8; p++) { sv += acc[c][p]; qv += acc[c][p] * acc[c][p]; }
        red[(c0 + c) * 33 + pg] = sv;
        red[1056 + (c0 + c) * 33 + pg] = qv;
    }
    __syncthreads();
    if (t < 64) {
        int co = t & 31, v = t >> 5;
        const float* base = red + v * 1056 + co * 33;
        float sum = 0.f;
        #pragma unroll
        for (int i = 0; i < 32; i++) sum += base[i];
        atomicAdd((v ? sqsum : ssum) + cbase + co, sum);
    }
}

// ---------------- finalize BN1 ----------------
__global__ void k_finalize(const float* __restrict__ s, const float* __restrict__ q,
                           const float* __restrict__ g, const float* __restrict__ be,
                           float* __restrict__ sc, float* __restrict__ sh, int C) {
    int c = threadIdx.x;
    if (c >= C) return;
    const float invN = 1.f / 262144.f;
    float m = s[c] * invN;
    float v = fmaxf(q[c] * invN - m * m, 0.f);
    float scale = g[c] * rsqrtf(v + EPSV);
    sc[c] = scale;
    sh[c] = be[c] - m * scale;
}

// ---------------- BN+ReLU fp32 (features, in place; finalize fused) ---------
__global__ __launch_bounds__(256) void k_bnrelu(float4* __restrict__ buf,
                                                const float* __restrict__ s,
                                                const float* __restrict__ q,
                                                const float* __restrict__ g,
                                                const float* __restrict__ be, int C) {
    size_t i = (size_t)blockIdx.x * 256 + threadIdx.x;
    int c = (int)(i >> 14) % C;
    const float invN = 1.f / 262144.f;
    float m = s[c] * invN;
    float var = fmaxf(q[c] * invN - m * m, 0.f);
    float sc = g[c] * rsqrtf(var + EPSV);
    float sh = be[c] - m * sc;
    float4 r = buf[i];
    float4 o;
    o.x = fmaxf(r.x * sc + sh, 0.f);
    o.y = fmaxf(r.y * sc + sh, 0.f);
    o.z = fmaxf(r.z * sc + sh, 0.f);
    o.w = fmaxf(r.w * sc + sh, 0.f);
    buf[i] = o;
}

// ---------------- per-channel stats over raw conv2 out ----------------
__global__ __launch_bounds__(256) void k_stats(const float* __restrict__ raw,
                                               float* __restrict__ ssum,
                                               float* __restrict__ sqsum) {
    const int co = blockIdx.x, seg = blockIdx.y;
    const int t = threadIdx.x;
    __shared__ float red[8];
    float s = 0.f, q = 0.f;
    for (int b = 0; b < 4; b++) {
        const float4* p = (const float4*)(raw + ((size_t)(b * 128 + co) * HWX) + seg * 8192);
        for (int i = t; i < 2048; i += 256) {
            float4 v = p[i];
            s += v.x + v.y + v.z + v.w;
            q += v.x * v.x + v.y * v.y + v.z * v.z + v.w * v.w;
        }
    }
    #pragma unroll
    for (int off = 32; off; off >>= 1) {
        s += __shfl_down(s, off, 64);
        q += __shfl_down(q, off, 64);
    }
    int lane = t & 63, wv = t >> 6;
    if (lane == 0) { red[wv] = s; red[4 + wv] = q; }
    __syncthreads();
    if (t == 0) atomicAdd(&ssum[co], red[0] + red[1] + red[2] + red[3]);
    else if (t == 1) atomicAdd(&sqsum[co], red[4] + red[5] + red[6] + red[7]);
}

// ---------------- weight pre-tiling ----------------
// match: wtile[(ch*2+plane)*9984 + (kw*64+co)*52 + kh*16+cil], ch=ci/16, 8 chunks
__global__ void k_prep_w(const float* __restrict__ wcat, u16* __restrict__ wtile) {
    int i = blockIdx.x * 256 + threadIdx.x;
    if (i >= 159744) return;
    int ch = i / 19968, rem = i - ch * 19968;
    int pl = rem / 9984; rem -= pl * 9984;
    int kwco = rem / 52, k = rem - kwco * 52;
    int kw = kwco >> 6, co = kwco & 63;
    u16 v = 0;
    if (k < 48 && co < 62) {
        int kh = k >> 4, ci = ch * 16 + (k & 15);
        float f = wcat[(size_t)co * 1152 + ci * 9 + kh * 3 + kw];
        u16 hv = f2u(f);
        v = pl ? f2u(f - u2f(hv)) : hv;
    }
    wtile[i] = v;
}
// conv2: wtile2[ch*19968 + (kw*128+co)*52 + kh*16+cil], 4 chunks of 16 ci
__global__ void k_prep_w2(const float* __restrict__ w2, u16* __restrict__ wtile2) {
    int i = blockIdx.x * 256 + threadIdx.x;
    if (i >= 79872) return;                 // 4 * 3*128*52
    int ch = i / 19968, rem = i - ch * 19968;
    int kwco = rem / 52, k = rem - kwco * 52;
    int kw = kwco >> 7, co = kwco & 127;
    u16 v = 0;
    if (k < 48) {
        int kh = k >> 4, ci = ch * 16 + (k & 15);
        v = f2u(w2[((size_t)co * 64 + ci) * 9 + kh * 3 + kw]);
    }
    wtile2[i] = v;
}
// heads: whl[ch*3840 + pl*1920 + co*20 + kloc], 12 chunks of 16 k, 96 rows (68 used)
__global__ void k_prep_wh(const float* __restrict__ qa1w, const float* __restrict__ clsw,
                          u16* __restrict__ whl) {
    int i = blockIdx.x * 256 + threadIdx.x;
    if (i >= 46080) return;
    int ch = i / 3840, rem = i - ch * 3840;
    int pl = rem / 1920; rem -= pl * 1920;
    int co = rem / 20, kloc = rem - co * 20;
    u16 v = 0;
    int k = ch * 16 + kloc;
    if (kloc < 16 && k < 190 && co < 68) {
        float f = (co < 64) ? qa1w[co * 190 + k] : clsw[(co - 64) * 190 + k];
        u16 hv = f2u(f);
        v = pl ? f2u(f - u2f(hv)) : hv;
    }
    whl[i] = v;
}

// ---- x prefetch helpers ----------------------------------------------------
// conv2: loads RAW conv1 bf16 and applies BN1+ReLU inline (bit-identical to
// the former k_bnrelu_h pass: u2f -> fma(sc,sh) -> relu -> f2u). scl/shl are
// LDS pointers (same addr across lanes -> broadcast, free).
__device__ __forceinline__ void load_x_c2(const u16* __restrict__ hb, int b, int ch,
                                          int h, int t,
                                          const float* __restrict__ scl,
                                          const float* __restrict__ shl,
                                          unsigned xp[24]) {
    #pragma unroll
    for (int r = 0; r < 3; r++) {
        int hh = h + r - 1;
        bool vr = (unsigned)hh < 256u;
        if (vr) {
            const u16* base = hb + ((size_t)(b * 64 + ch * 16) << 16)
                            + ((size_t)hh << 8) + t;
            #pragma unroll
            for (int ci = 0; ci < 16; ci += 2) {
                float va = u2f(base[(size_t)ci << 16]);
                float vc = u2f(base[(size_t)(ci + 1) << 16]);
                va = fmaxf(va * scl[ci] + shl[ci], 0.f);
                vc = fmaxf(vc * scl[ci + 1] + shl[ci + 1], 0.f);
                unsigned a = f2u(va), c = f2u(vc);
                xp[(r * 16 + ci) >> 1] = a | (c << 16);
            }
        } else {
            #pragma unroll
            for (int ci = 0; ci < 16; ci += 2) xp[(r * 16 + ci) >> 1] = 0u;
        }
    }
}

// h-tiled match: load 4 input rows (h0-1..h0+2) and split to packed bf16
// hi/lo planes at load time -> 32+32 u32 live regs instead of 64 f32.
__device__ __forceinline__ void load_split_match(const float* __restrict__ feat,
                                                 int b, int ch, int h0, int t,
                                                 unsigned xhi[32], unsigned xlo[32]) {
    #pragma unroll
    for (int r = 0; r < 4; r++) {
        int hh = h0 + r - 1;
        if ((unsigned)hh < 256u) {          // block-uniform branch
            const float* base = feat + ((size_t)(b * 128 + ch * 16) << 16)
                              + ((size_t)hh << 8) + t;
            float v[16];
            #pragma unroll
            for (int ci = 0; ci < 16; ci++)
                v[ci] = base[(size_t)ci << 16];
            #pragma unroll
            for (int ci = 0; ci < 16; ci += 2) {
                u16 ha = f2u(v[ci]), hb2 = f2u(v[ci + 1]);
                unsigned la = f2u(v[ci] - u2f(ha));
                unsigned lb = f2u(v[ci + 1] - u2f(hb2));
                xhi[(r * 16 + ci) >> 1] = (unsigned)ha | ((unsigned)hb2 << 16);
                xlo[(r * 16 + ci) >> 1] = la | (lb << 16);
            }
        }
    }
}

// ---------------- conv2 MFMA: 64->128, raw bf16 in + inline BN1, fp32 out ---
__global__ __launch_bounds__(256, 2) void k_conv2_mf(
    const u16* __restrict__ hb, const u16* __restrict__ wtile2,
    const float* __restrict__ sc1, const float* __restrict__ sh1,
    const float* __restrict__ bias, float* __restrict__ out)
{
    const int h = blockIdx.x, b = blockIdx.y;
    const int t = threadIdx.x, l = t & 63, wv = t >> 6;
    const int kg = (l >> 5) * 8, nn = l & 31;

    __shared__ __align__(16) u16 xs[258 * 52];
    __shared__ __align__(16) u16 wl[3 * 128 * 52];
    __shared__ float scs[64], shs[64];

    f16v acc[2][4];
    #pragma unroll
    for (int pt = 0; pt < 2; pt++)
        #pragma unroll
        for (int s = 0; s < 4; s++)
            #pragma unroll
            for (int r = 0; r < 16; r++) acc[pt][s][r] = 0.f;

    // one-time zero fill (pads + out-of-range rows persist as 0)
    for (int i = t; i < 258 * 52 / 4; i += 256)
        ((ushort4*)xs)[i] = ushort4{0, 0, 0, 0};
    if (t < 64) { scs[t] = sc1[t]; shs[t] = sh1[t]; }
    __syncthreads();

    unsigned xp[24];
    load_x_c2(hb, b, 0, h, t, scs, shs, xp);

    for (int ch = 0; ch < 4; ch++) {
        {
            const int4* src = (const int4*)(wtile2 + (size_t)ch * 19968);
            for (int i = t; i < 2496; i += 256) ((int4*)wl)[i] = src[i];
        }
        #pragma unroll
        for (int r = 0; r < 3; r++) {
            if ((unsigned)(h + r - 1) < 256u) {
                #pragma unroll
                for (int g = 0; g < 4; g++) {
                    int i0 = r * 16 + g * 4;
                    uint2 hp;
                    hp.x = xp[i0 >> 1];
                    hp.y = xp[(i0 >> 1) + 1];
                    *(uint2*)&xs[(size_t)(t + 1) * 52 + i0] = hp;
                }
            }
        }
        __syncthreads();
        if (ch < 3)   // overlap with MFMA (BN math rides the VALU pipe)
            load_x_c2(hb, b, ch + 1, h, t, scs + (ch + 1) * 16, shs + (ch + 1) * 16, xp);
        #pragma unroll
        for (int kw = 0; kw < 3; kw++) {
            #pragma unroll
            for (int ks = 0; ks < 3; ks++) {
                int k0 = ks * 16 + kg;
                s8v af[4], bf[2];
                #pragma unroll
                for (int s = 0; s < 4; s++)
                    af[s] = ld8(&wl[(kw * 128 + s * 32 + nn) * 52 + k0]);
                #pragma unroll
                for (int pt = 0; pt < 2; pt++)
                    bf[pt] = ld8(&xs[((wv * 2 + pt) * 32 + nn + kw) * 52 + k0]);
                #pragma unroll
                for (int pt = 0; pt < 2; pt++)
                    #pragma unroll
                    for (int s = 0; s < 4; s++)
                        acc[pt][s] = __builtin_amdgcn_mfma_f32_32x32x16_bf16(
                            af[s], bf[pt], acc[pt][s], 0, 0, 0);
            }
        }
        __syncthreads();
    }

    #pragma unroll
    for (int pt = 0; pt < 2; pt++) {
        int px = (wv * 2 + pt) * 32 + nn;
        #pragma unroll
        for (int s = 0; s < 4; s++) {
            #pragma unroll
            for (int r = 0; r < 16; r++) {
                int co = s * 32 + (r & 3) + 8 * (r >> 2) + 4 * (l >> 5);
                out[(((size_t)b * 128 + co) * 256 + h) * 256 + px] = acc[pt][s][r] + bias[co];
            }
        }
    }
}

// ---------------- match MFMA: 128->62, 3-term split, h-tiled x2 -------------
__global__ __launch_bounds__(256, 2) void k_match_mf(
    const float* __restrict__ feat, const u16* __restrict__ wtile,
    float* __restrict__ out_all, float* __restrict__ out_anom)
{
    const int h0 = blockIdx.x * 2, b = blockIdx.y;
    const int t = threadIdx.x, l = t & 63, wv = t >> 6;
    const int kg = (l >> 5) * 8, nn = l & 31;

    __shared__ __align__(16) u16 xr[4 * 258 * 20];   // 41,280 B (hi then lo, per chunk)
    __shared__ __align__(16) u16 wl[2 * 9984];       // 39,936 B (hi, lo weights for chunk)

    f16v acc[2][2][2];   // [o][pt][s]
    #pragma unroll
    for (int o = 0; o < 2; o++)
        #pragma unroll
        for (int pt = 0; pt < 2; pt++)
            #pragma unroll
            for (int s = 0; s < 2; s++)
                #pragma unroll
                for (int r = 0; r < 16; r++) acc[o][pt][s][r] = 0.f;

    // one-time zero fill (px halos + out-of-range input rows persist as 0)
    for (int i = t; i < 4 * 258 * 20 / 4; i += 256)
        ((ushort4*)xr)[i] = ushort4{0, 0, 0, 0};
    __syncthreads();

    unsigned xhi[32], xlo[32];
    load_split_match(feat, b, 0, h0, t, xhi, xlo);

    for (int ch = 0; ch < 8; ch++) {
        // weights: both planes contiguous, 2496 int4
        {
            const int4* src = (const int4*)(wtile + (size_t)ch * 2 * 9984);
            for (int i = t; i < 2496; i += 256) ((int4*)wl)[i] = src[i];
        }
        // ---- hi planes write (packed b64, px slot t+1)
        #pragma unroll
        for (int r = 0; r < 4; r++) {
            if ((unsigned)(h0 + r - 1) < 256u) {       // block-uniform branch
                u16* dst = xr + r * 5160 + (t + 1) * 20;
                #pragma unroll
                for (int g = 0; g < 4; g++) {
                    uint2 hp;
                    hp.x = xhi[r * 8 + g * 2];
                    hp.y = xhi[r * 8 + g * 2 + 1];
                    *(uint2*)&dst[g * 4] = hp;
                }
            }
        }
        __syncthreads();
        // ---- hi-MFMA: Wh*Xh + Wl*Xh for both output rows
        #pragma unroll
        for (int kw = 0; kw < 3; kw++) {
            #pragma unroll
            for (int ks = 0; ks < 3; ks++) {
                int k0 = ks * 16 + kg;
                s8v ah0 = ld8(&wl[(kw * 64 + nn) * 52 + k0]);
                s8v ah1 = ld8(&wl[(kw * 64 + 32 + nn) * 52 + k0]);
                s8v al0 = ld8(&wl[9984 + (kw * 64 + nn) * 52 + k0]);
                s8v al1 = ld8(&wl[9984 + (kw * 64 + 32 + nn) * 52 + k0]);
                #pragma unroll
                for (int o = 0; o < 2; o++) {
                    #pragma unroll
                    for (int pt = 0; pt < 2; pt++) {
                        s8v xf = ld8(&xr[(ks + o) * 5160
                                         + ((wv * 2 + pt) * 32 + nn + kw) * 20 + kg]);
                        acc[o][pt][0] = __builtin_amdgcn_mfma_f32_32x32x16_bf16(ah0, xf, acc[o][pt][0], 0, 0, 0);
                        acc[o][pt][0] = __builtin_amdgcn_mfma_f32_32x32x16_bf16(al0, xf, acc[o][pt][0], 0, 0, 0);
                        acc[o][pt][1] = __builtin_amdgcn_mfma_f32_32x32x16_bf16(ah1, xf, acc[o][pt][1], 0, 0, 0);
                        acc[o][pt][1] = __builtin_amdgcn_mfma_f32_32x32x16_bf16(al1, xf, acc[o][pt][1], 0, 0, 0);
                    }
                }
            }
        }
        __syncthreads();
        // ---- lo planes write (pure unpack from xlo)
        #pragma unroll
        for (int r = 0; r < 4; r++) {
            if ((unsigned)(h0 + r - 1) < 256u) {
                u16* dst = xr + r * 5160 + (t + 1) * 20;
                #pragma unroll
                for (int g = 0; g < 4; g++) {
                    uint2 lp;
                    lp.x = xlo[r * 8 + g * 2];
                    lp.y = xlo[r * 8 + g * 2 + 1];
                    *(uint2*)&dst[g * 4] = lp;
                }
            }
        }
        __syncthreads();
        // ---- lo-MFMA: Wh*Xl; prefetch+split next chunk (xhi/xlo free now)
        if (ch < 7) load_split_match(feat, b, ch + 1, h0, t, xhi, xlo);
        #pragma unroll
        for (int kw = 0; kw < 3; kw++) {
            #pragma unroll
            for (int ks = 0; ks < 3; ks++) {
                int k0 = ks * 16 + kg;
                s8v ah0 = ld8(&wl[(kw * 64 + nn) * 52 + k0]);
                s8v ah1 = ld8(&wl[(kw * 64 + 32 + nn) * 52 + k0]);
                #pragma unroll
                for (int o = 0; o < 2; o++) {
                    #pragma unroll
                    for (int pt = 0; pt < 2; pt++) {
                        s8v xf = ld8(&xr[(ks + o) * 5160
                                         + ((wv * 2 + pt) * 32 + nn + kw) * 20 + kg]);
                        acc[o][pt][0] = __builtin_amdgcn_mfma_f32_32x32x16_bf16(ah0, xf, acc[o][pt][0], 0, 0, 0);
                        acc[o][pt][1] = __builtin_amdgcn_mfma_f32_32x32x16_bf16(ah1, xf, acc[o][pt][1], 0, 0, 0);
                    }
                }
            }
        }
        __syncthreads();
    }

    #pragma unroll
    for (int o = 0; o < 2; o++) {
        int h = h0 + o;
        #pragma unroll
        for (int pt = 0; pt < 2; pt++) {
            int px = (wv * 2 + pt) * 32 + nn;
            #pragma unroll
            for (int s = 0; s < 2; s++) {
                #pragma unroll
                for (int r = 0; r < 16; r++) {
                    int cm = s * 32 + (r & 3) + 8 * (r >> 2) + 4 * (l >> 5);
                    float sg = 1.f / (1.f + __expf(-acc[o][pt][s][r]));
                    if (cm < 30)
                        out_all[(((size_t)b * 30 + cm) * 256 + h) * 256 + px] = sg;
                    else if (cm < 62)
                        out_anom[(((size_t)b * 32 + cm - 30) * 256 + h) * 256 + px] = sg;
                }
            }
        }
    }
}

// ---------------- heads MFMA: 190->68 1x1, 3-term split ----------------
__device__ __forceinline__ void load_x_heads(const float* __restrict__ fb,
                                             const float* __restrict__ ab,
                                             const float* __restrict__ nb,
                                             int ch, float xv[16]) {
    #pragma unroll
    for (int ci = 0; ci < 16; ci++) {
        int k = ch * 16 + ci;
        float v;
        if (k < 128)      v = fb[(size_t)k << 16];
        else if (k < 158) v = ab[(size_t)(k - 128) << 16];
        else if (k < 190) v = nb[(size_t)(k - 158) << 16];
        else              v = 0.f;
        xv[ci] = v;
    }
}

__global__ __launch_bounds__(256, 2) void k_heads_mf(
    const float* __restrict__ dout, const u16* __restrict__ whl,
    const float* __restrict__ qa1b, const float* __restrict__ qa2w,
    const float* __restrict__ qa2b, const float* __restrict__ clsb,
    float* __restrict__ out)
{
    const int h = blockIdx.x, b = blockIdx.y;
    const int t = threadIdx.x, l = t & 63, wv = t >> 6;
    const int kg = (l >> 5) * 8, nn = l & 31;

    __shared__ __align__(16) u16 xh[256 * 20];    // hi plane, row px, pad 20
    __shared__ __align__(16) u16 xl[256 * 20];    // lo plane
    __shared__ __align__(16) u16 wl2[2 * 1920];   // hi, lo weights for chunk
    __shared__ float lb[69];                      // qa1b[64], clsb[4], qa2b
    __shared__ float lw2[64];                     // qa2w

    if (t < 64) { lb[t] = qa1b[t]; lw2[t] = qa2w[t]; }
    if (t < 4) lb[64 + t] = clsb[t];
    if (t == 0) lb[68] = qa2b[0];

    f16v acc[3][2];
    #pragma unroll
    for (int s = 0; s < 3; s++)
        #pragma unroll
        for (int pt = 0; pt < 2; pt++)
            #pragma unroll
            for (int r = 0; r < 16; r++) acc[s][pt][r] = 0.f;

    const float* fb = dout + O0 + (((size_t)b * 128) << 16) + ((size_t)h << 8) + t;
    const float* ab = dout + O3 + (((size_t)b * 30) << 16) + ((size_t)h << 8) + t;
    const float* nb = dout + O4 + (((size_t)b * 32) << 16) + ((size_t)h << 8) + t;

    float xv[16];
    load_x_heads(fb, ab, nb, 0, xv);

    #pragma unroll
    for (int ch = 0; ch < 12; ch++) {
        {
            const int4* src = (const int4*)(whl + (size_t)ch * 3840);
            for (int i = t; i < 480; i += 256) ((int4*)wl2)[i] = src[i];
        }
        #pragma unroll
        for (int g = 0; g < 4; g++) {
            int i0 = g * 4;
            u16 h0 = f2u(xv[i0 + 0]), h1 = f2u(xv[i0 + 1]);
            u16 h2 = f2u(xv[i0 + 2]), h3 = f2u(xv[i0 + 3]);
            uint2 hp, lp;
            hp.x = (unsigned)h0 | ((unsigned)h1 << 16);
            hp.y = (unsigned)h2 | ((unsigned)h3 << 16);
            lp.x = (unsigned)f2u(xv[i0 + 0] - u2f(h0))
                 | ((unsigned)f2u(xv[i0 + 1] - u2f(h1)) << 16);
            lp.y = (unsigned)f2u(xv[i0 + 2] - u2f(h2))
                 | ((unsigned)f2u(xv[i0 + 3] - u2f(h3)) << 16);
            *(uint2*)&xh[t * 20 + i0] = hp;
            *(uint2*)&xl[t * 20 + i0] = lp;
        }
        __syncthreads();
        if (ch < 11) load_x_heads(fb, ab, nb, ch + 1, xv);   // overlap with MFMA
        s8v xfh[2], xfl[2];
        #pragma unroll
        for (int pt = 0; pt < 2; pt++) {
            int row = (wv * 2 + pt) * 32 + nn;
            xfh[pt] = ld8(&xh[row * 20 + kg]);
            xfl[pt] = ld8(&xl[row * 20 + kg]);
        }
        #pragma unroll
        for (int s = 0; s < 3; s++) {
            s8v awh = ld8(&wl2[(s * 32 + nn) * 20 + kg]);
            s8v awl = ld8(&wl2[1920 + (s * 32 + nn) * 20 + kg]);
            #pragma unroll
            for (int pt = 0; pt < 2; pt++) {
                acc[s][pt] = __builtin_amdgcn_mfma_f32_32x32x16_bf16(awh, xfh[pt], acc[s][pt], 0, 0, 0);
                acc[s][pt] = __builtin_amdgcn_mfma_f32_32x32x16_bf16(awl, xfh[pt], acc[s][pt], 0, 0, 0);
                acc[s][pt] = __builtin_amdgcn_mfma_f32_32x32x16_bf16(awh, xfl[pt], acc[s][pt], 0, 0, 0);
            }
        }
        __syncthreads();
    }

    // ---- epilogue: qa dot + sigmoid, cls softmax/sigmoid ----
    const int hi = l >> 5;
    #pragma unroll
    for (int pt = 0; pt < 2; pt++) {
        float qa_part = 0.f;
        #pragma unroll
        for (int m = 0; m < 2; m++)
            #pragma unroll
            for (int r = 0; r < 16; r++) {
                int row = m * 32 + (r & 3) + 8 * (r >> 2) + 4 * hi;
                float v = acc[m][pt][r] + lb[row];
                qa_part += fmaxf(v, 0.f) * lw2[row];
            }
        qa_part += __shfl_xor(qa_part, 32, 64);
        if (hi == 0) {
            int px = (wv * 2 + pt) * 32 + nn;
            size_t hw = (size_t)h * 256 + px;
            float quality = 1.f / (1.f + __expf(-(qa_part + lb[68])));
            float c0 = acc[2][pt][0] + lb[64];
            float c1 = acc[2][pt][1] + lb[65];
            float c2 = acc[2][pt][2] + lb[66];
            float c3 = acc[2][pt][3] + lb[67];
            float m0 = fmaxf(c0, fmaxf(c1, c2));
            float e0 = __expf(c0 - m0), e1 = __expf(c1 - m0), e2 = __expf(c2 - m0);
            float inv = 1.f / (e0 + e1 + e2);
            out[O1 + ((size_t)b * 3 + 0) * HWX + hw] = c0;
            out[O1 + ((size_t)b * 3 + 1) * HWX + hw] = c1;
            out[O1 + ((size_t)b * 3 + 2) * HWX + hw] = c2;
            out[O2 + (size_t)b * HWX + hw] = c3;
            out[O5 + (size_t)b * HWX + hw] = quality;
            out[O6 + ((size_t)b * 3 + 0) * HWX + hw] = e0 * inv;
            out[O6 + ((size_t)b * 3 + 1) * HWX + hw] = e1 * inv;
            out[O6 + ((size_t)b * 3 + 2) * HWX + hw] = e2 * inv;
            out[O7 + (size_t)b * HWX + hw] = 1.f / (1.f + __expf(-c3));
        }
    }
}

extern "C" void kernel_launch(void* const* d_in, const int* in_sizes, int n_in,
                              void* d_out, int out_size, void* d_ws, size_t ws_size,
                              hipStream_t stream) {
    (void)in_sizes; (void)n_in; (void)out_size; (void)ws_size;
    const float* x    = (const float*)d_in[0];
    const float* w1   = (const float*)d_in[1];
    const float* b1   = (const float*)d_in[2];
    const float* g1   = (const float*)d_in[3];
    const float* be1  = (const float*)d_in[4];
    const float* w2   = (const float*)d_in[5];
    const float* b2   = (const float*)d_in[6];
    const float* g2   = (const float*)d_in[7];
    const float* be2  = (const float*)d_in[8];
    const float* core = (const float*)d_in[9];
    const float* clad = (const float*)d_in[10];
    const float* ferr = (const float*)d_in[11];
    const float* anom = (const float*)d_in[12];
    const float* qa1w = (const float*)d_in[13];
    const float* qa1b = (const float*)d_in[14];
    const float* qa2w = (const float*)d_in[15];
    const float* qa2b = (const float*)d_in[16];
    const float* clsw = (const float*)d_in[17];
    const float* clsb = (const float*)d_in[18];

    char* ws = (char*)d_ws;
    float* stats = (float*)ws;
    float* s1 = stats + 0;
    float* q1 = stats + 64;
    float* s2 = stats + 128;
    float* q2 = stats + 256;
    float* sc1 = stats + 384;
    float* sh1 = stats + 448;
    u16*   hraw   = (u16*)(ws + 4096);                // 33,554,432 B
    float* wcat   = (float*)(ws + 33558528ull);       // 285,696 B (dead after k_prep_w -> reused as whl)
    u16*   wtile2 = (u16*)(ws + 33844224ull);         // 79,872*2 B
    u16*   wtile  = (u16*)(ws + 34004224ull);         // 159,744*2 B
    u16*   whl    = (u16*)wcat;                       // 92,160 B, alias (safe: after k_prep_w)
    float* dout = (float*)d_out;

    hipMemsetAsync(stats, 0, 384 * sizeof(float), stream);
    hipMemcpyAsync(wcat,             core, 10 * 1152 * 4, hipMemcpyDeviceToDevice, stream);
    hipMemcpyAsync(wcat + 10 * 1152, clad, 10 * 1152 * 4, hipMemcpyDeviceToDevice, stream);
    hipMemcpyAsync(wcat + 20 * 1152, ferr, 10 * 1152 * 4, hipMemcpyDeviceToDevice, stream);
    hipMemcpyAsync(wcat + 30 * 1152, anom, 32 * 1152 * 4, hipMemcpyDeviceToDevice, stream);

    dim3 blk(256);
    k_prep_w2<<<312, blk, 0, stream>>>(w2, wtile2);
    k_prep_w<<<624, blk, 0, stream>>>(wcat, wtile);
    k_prep_wh<<<180, blk, 0, stream>>>(qa1w, clsw, whl);   // overwrites wcat (dead)

    k_conv1<<<dim3(256, 2, 4), blk, 0, stream>>>(x, w1, b1, hraw, s1, q1);
    k_finalize<<<1, 128, 0, stream>>>(s1, q1, g1, be1, sc1, sh1, 64);

    k_conv2_mf<<<dim3(256, 4), blk, 0, stream>>>(hraw, wtile2, sc1, sh1, b2, dout + O0);
    k_stats<<<dim3(128, 8), blk, 0, stream>>>(dout + O0, s2, q2);
    k_bnrelu<<<32768, blk, 0, stream>>>((float4*)(dout + O0), s2, q2, g2, be2, 128);

    k_match_mf<<<dim3(128, 4), blk, 0, stream>>>(dout + O0, wtile, dout + O3, dout + O4);
    k_heads_mf<<<dim3(256, 4), blk, 0, stream>>>(dout, whl, qa1b, qa2w, qa2b, clsb, dout);
}